// Round 8
// baseline (212.842 us; speedup 1.0000x reference)
//
#include <hip/hip_runtime.h>

#define NB 8
#define NN 2048
#define NM 8192
#define NC 64
#define ND 64
#define NK 16

#define PARTS 8     // lanes per query
#define PPT 256     // points per lane (NN / PARTS)
#define CHUNK 260   // padded chunk stride in floats: 260%32==4 -> parts on
                    // distinct bank-quads -> conflict-free ds_read_b128
#define QPB 64      // queries per block (512 threads / 8 parts)
#define NG 8        // groups of 32 points per lane
#define CAP 64      // candidate slots per query (overflow prob ~e^-40 + exact fallback)

#define KB (NM / QPB)       // knn blocks per batch (128) -- FIRST in grid
#define FB (NN / 64)        // feats blocks per batch (32) -- after knn
// knn LDS: 3*8*260*4 (24960) + 64*64*2 (8192) + 64*4 (256) = 33408 B
// -> 4 blocks/CU * 8 waves = 32 waves/CU (max). feats path uses 17408 B.
#define SMEM_BYTES 33408

__device__ __forceinline__ float d2rn(float qx, float qy, float qz, float x,
                                      float y, float z) {
  const float dx = __fsub_rn(qx, x);
  const float dy = __fsub_rn(qy, y);
  const float dz = __fsub_rn(qz, z);
  return __fadd_rn(__fadd_rn(__fmul_rn(dx, dx), __fmul_rn(dy, dy)),
                   __fmul_rn(dz, dz));
}

#define CE(a, i, j)                     \
  {                                     \
    const float lo = fminf(a[i], a[j]); \
    const float hi = fmaxf(a[i], a[j]); \
    a[i] = lo;                          \
    a[j] = hi;                          \
  }

// Batcher odd-even sort of d[8] ascending (19 comparators)
#define SORT8(d)                                  \
  CE(d, 0, 1) CE(d, 2, 3) CE(d, 4, 5) CE(d, 6, 7) \
  CE(d, 0, 2) CE(d, 1, 3) CE(d, 4, 6) CE(d, 5, 7) \
  CE(d, 1, 2) CE(d, 5, 6)                         \
  CE(d, 0, 4) CE(d, 1, 5) CE(d, 2, 6) CE(d, 3, 7) \
  CE(d, 2, 4) CE(d, 3, 5)                         \
  CE(d, 1, 2) CE(d, 3, 4) CE(d, 5, 6)

// bitonic sort of L[16] (input bitonic) ascending: 32 comparators
#define BITONIC16(L)                                                      \
  CE(L, 0, 8) CE(L, 1, 9) CE(L, 2, 10) CE(L, 3, 11) CE(L, 4, 12)          \
  CE(L, 5, 13) CE(L, 6, 14) CE(L, 7, 15)                                  \
  CE(L, 0, 4) CE(L, 1, 5) CE(L, 2, 6) CE(L, 3, 7) CE(L, 8, 12)            \
  CE(L, 9, 13) CE(L, 10, 14) CE(L, 11, 15)                                \
  CE(L, 0, 2) CE(L, 1, 3) CE(L, 4, 6) CE(L, 5, 7) CE(L, 8, 10)            \
  CE(L, 9, 11) CE(L, 12, 14) CE(L, 13, 15)                                \
  CE(L, 0, 1) CE(L, 2, 3) CE(L, 4, 5) CE(L, 6, 7) CE(L, 8, 9)             \
  CE(L, 10, 11) CE(L, 12, 13) CE(L, 14, 15)

__device__ __forceinline__ void dist8(const float* px, const float* py,
                                      const float* pz, int base, float qx,
                                      float qy, float qz, float d[8]) {
  const float4 X0 = *(const float4*)&px[base];
  const float4 X1 = *(const float4*)&px[base + 4];
  const float4 Y0 = *(const float4*)&py[base];
  const float4 Y1 = *(const float4*)&py[base + 4];
  const float4 Z0 = *(const float4*)&pz[base];
  const float4 Z1 = *(const float4*)&pz[base + 4];
  d[0] = d2rn(qx, qy, qz, X0.x, Y0.x, Z0.x);
  d[1] = d2rn(qx, qy, qz, X0.y, Y0.y, Z0.y);
  d[2] = d2rn(qx, qy, qz, X0.z, Y0.z, Z0.z);
  d[3] = d2rn(qx, qy, qz, X0.w, Y0.w, Z0.w);
  d[4] = d2rn(qx, qy, qz, X1.x, Y1.x, Z1.x);
  d[5] = d2rn(qx, qy, qz, X1.y, Y1.y, Z1.y);
  d[6] = d2rn(qx, qy, qz, X1.z, Y1.z, Z1.z);
  d[7] = d2rn(qx, qy, qz, X1.w, Y1.w, Z1.w);
}

__device__ __forceinline__ float min8(const float d[8]) {
  return fminf(fminf(fminf(d[0], d[1]), fminf(d[2], d[3])),
               fminf(fminf(d[4], d[5]), fminf(d[6], d[7])));
}

// ---------------------------------------------------------------------------
// Fused kernel, 512 threads: blockIdx.x < KB -> kNN (verbatim r2 per-thread
// algorithm, 8 waves/block -> 32 waves/CU); else -> feats/linear on t<256.
// ---------------------------------------------------------------------------
__global__ __launch_bounds__(512, 8) void fused_kernel(
    const float* __restrict__ features, const float* __restrict__ W1,
    const float* __restrict__ b1, float* __restrict__ out_feats,
    float* __restrict__ out_x, const float* __restrict__ xyz,
    const float* __restrict__ xyz_fp, float* __restrict__ out_knn) {
  __shared__ __align__(16) unsigned char smem[SMEM_BYTES];

  const int b = blockIdx.y;
  const int t = threadIdx.x;

  if (blockIdx.x >= KB) {
    // ============ feats + linear path (r7 body, threads 0..255) ============
    float(*tile)[68] = reinterpret_cast<float(*)[68]>(smem);  // 17408 B

    const int n0 = (blockIdx.x - KB) * 64;
    const int lane = t & 63;
    const int grp = (t >> 6) & 3;  // 0..3 for t<256

    if (t < 256) {
      for (int c = grp; c < NC; c += 4)
        tile[c][lane] = features[((size_t)(b * NC + c) * NN) + n0 + lane];
    }
    __syncthreads();
    if (t >= 256) return;

    // this thread's W1 row (w for d=lane, all c): 16 float4 in registers
    float4 wreg[16];
    {
      const float4* Wr = (const float4*)(W1 + lane * NC);
#pragma unroll
      for (int k = 0; k < 16; k++) wreg[k] = Wr[k];
    }

    for (int j = grp; j < 64; j += 4)
      out_feats[((size_t)(b * NN + n0 + j) * NC) + lane] = tile[lane][j];

    const int d = lane;
    float acc[16];
    const float bd = b1[d];
#pragma unroll
    for (int jj = 0; jj < 16; jj++) acc[jj] = bd;

    const float4* tv = (const float4*)&tile[0][0];
#pragma unroll
    for (int k = 0; k < 16; k++) {
#pragma unroll
      for (int cc = 0; cc < 4; cc++) {
        const int c = k * 4 + cc;
        const float w = (cc == 0)   ? wreg[k].x
                        : (cc == 1) ? wreg[k].y
                        : (cc == 2) ? wreg[k].z
                                    : wreg[k].w;
#pragma unroll
        for (int q = 0; q < 4; q++) {
          const float4 v = tv[c * 17 + grp * 4 + q];
          acc[q * 4 + 0] = fmaf(v.x, w, acc[q * 4 + 0]);
          acc[q * 4 + 1] = fmaf(v.y, w, acc[q * 4 + 1]);
          acc[q * 4 + 2] = fmaf(v.z, w, acc[q * 4 + 2]);
          acc[q * 4 + 3] = fmaf(v.w, w, acc[q * 4 + 3]);
        }
      }
    }
#pragma unroll
    for (int jj = 0; jj < 16; jj++) {
      const int j = grp * 16 + jj;
      out_x[((size_t)(b * NN + n0 + j) * ND) + d] = acc[jj];
    }
    return;
  }

  // ======================= kNN path (verbatim r2) =======================
  float* px = reinterpret_cast<float*>(smem);
  float* py = px + PARTS * CHUNK;
  float* pz = py + PARTS * CHUNK;
  unsigned short* cand =
      reinterpret_cast<unsigned short*>(smem + 3 * PARTS * CHUNK * 4);
  int* ccnt =
      reinterpret_cast<int*>(smem + 3 * PARTS * CHUNK * 4 + QPB * CAP * 2);

  const int ql = t >> 3;   // query-local 0..63
  const int part = t & 7;  // 0..7

  if (t < QPB) ccnt[t] = 0;

  // stage points SoA, chunked per part with +4 float pad
  const float* P = xyz + (size_t)b * NN * 3;
  for (int i = t; i < NN; i += 512) {
    const int slot = (i >> 8) * CHUNK + (i & 255);
    px[slot] = P[3 * i + 0];
    py[slot] = P[3 * i + 1];
    pz[slot] = P[3 * i + 2];
  }
  __syncthreads();

  const int q = blockIdx.x * QPB + ql;
  const float* Q = xyz_fp + ((size_t)b * NM + q) * 3;
  const float qx = Q[0], qy = Q[1], qz = Q[2];

  const int pbase = part * CHUNK;

  // ---- pass 1: group mins (8 groups of 32 points per lane) ----
  float gmin[NG];
#pragma unroll
  for (int g = 0; g < NG; g++) {
    float gm = 3.0e38f;
#pragma unroll
    for (int bb = 0; bb < 4; bb++) {
      float d[8];
      dist8(px, py, pz, pbase + g * 32 + bb * 8, qx, qy, qz, d);
      gm = fminf(gm, min8(d));
    }
    gmin[g] = gm;
  }

  // ---- T = 16th-smallest of the query's 64 group-mins ----
  float s[16];
  {
    float g8[NG];
#pragma unroll
    for (int g = 0; g < NG; g++) g8[g] = gmin[g];
    SORT8(g8)
#pragma unroll
    for (int j = 0; j < 8; j++) s[j] = g8[j];
#pragma unroll
    for (int j = 8; j < 16; j++) s[j] = 3.0e38f;
  }
#pragma unroll
  for (int mask = 1; mask <= 4; mask <<= 1) {
    float B[16];
#pragma unroll
    for (int j = 0; j < 16; j++) B[j] = __shfl_xor(s[j], mask, 64);
    float L[16];
#pragma unroll
    for (int j = 0; j < 16; j++) L[j] = fminf(s[j], B[15 - j]);
    BITONIC16(L)
#pragma unroll
    for (int j = 0; j < 16; j++) s[j] = L[j];
  }
  const float T = s[15];

  // ---- per-lane 8-bit pass mask ----
  unsigned m8 = 0;
#pragma unroll
  for (int g = 0; g < NG; g++) m8 |= (gmin[g] <= T) ? (1u << g) : 0u;

  // ---- butterfly-OR across the query's 8 lanes -> 64-bit group mask ----
  unsigned lo = (part < 4) ? (m8 << (8 * part)) : 0u;
  unsigned hi = (part >= 4) ? (m8 << (8 * (part - 4))) : 0u;
#pragma unroll
  for (int mk = 1; mk <= 4; mk <<= 1) {
    lo |= __shfl_xor(lo, mk, 64);
    hi |= __shfl_xor(hi, mk, 64);
  }
  const unsigned long long vm = ((unsigned long long)hi << 32) | lo;

  // ---- round-robin: k-th set bit -> lane (k & 7) ----
  unsigned long long mym = 0ull;
  {
    unsigned long long m = vm;
    int cnt = 0;
    while (m) {
      const unsigned long long lb = m & (0ull - m);
      if ((cnt & 7) == part) mym |= lb;
      m ^= lb;
      cnt++;
    }
  }

  // ---- pass 2: scan assigned groups (any chunk), collect candidates ----
  while (mym) {
    const int gid = __ffsll(mym) - 1;
    mym &= mym - 1;
    const int gb = (gid >> 3) * CHUNK + (gid & 7) * 32;
    const int ib = (gid >> 3) * PPT + (gid & 7) * 32;
#pragma unroll
    for (int bb = 0; bb < 4; bb++) {
      float d[8];
      dist8(px, py, pz, gb + bb * 8, qx, qy, qz, d);
      if (min8(d) <= T) {
#pragma unroll
        for (int j = 0; j < 8; j++) {
          if (d[j] <= T) {
            const int pos = atomicAdd(&ccnt[ql], 1);
            if (pos < CAP)
              cand[ql * CAP + pos] = (unsigned short)(ib + bb * 8 + j);
          }
        }
      }
    }
  }
  __syncthreads();

  // ---- phase 3: exact stable top-16 by (d2, idx) u64 keys ----
  if (part == 0) {
    const int cnt = ccnt[ql];
    unsigned long long kb[NK];
#pragma unroll
    for (int j = 0; j < NK; j++) kb[j] = ~0ULL;

    if (cnt <= CAP) {
      for (int c = 0; c < cnt; c++) {
        const int i = cand[ql * CAP + c];
        const int slot = (i >> 8) * CHUNK + (i & 255);
        const float d2 = d2rn(qx, qy, qz, px[slot], py[slot], pz[slot]);
        unsigned long long kk =
            ((unsigned long long)__float_as_uint(d2) << 32) | (unsigned)i;
        if (kk < kb[NK - 1]) {
#pragma unroll
          for (int j = 0; j < NK; j++) {
            const bool c2 = kk < kb[j];
            const unsigned long long lo2 = c2 ? kk : kb[j];
            const unsigned long long hi2 = c2 ? kb[j] : kk;
            kb[j] = lo2;
            kk = hi2;
          }
        }
      }
    } else {
      // overflow fallback (astronomically rare): exact scan of all points
      for (int i = 0; i < NN; i++) {
        const int slot = (i >> 8) * CHUNK + (i & 255);
        const float d2 = d2rn(qx, qy, qz, px[slot], py[slot], pz[slot]);
        unsigned long long kk =
            ((unsigned long long)__float_as_uint(d2) << 32) | (unsigned)i;
        if (kk < kb[NK - 1]) {
#pragma unroll
          for (int j = 0; j < NK; j++) {
            const bool c2 = kk < kb[j];
            const unsigned long long lo2 = c2 ? kk : kb[j];
            const unsigned long long hi2 = c2 ? kb[j] : kk;
            kb[j] = lo2;
            kk = hi2;
          }
        }
      }
    }
#pragma unroll
    for (int j = 0; j < NK; j++)
      cand[ql * CAP + j] = (unsigned short)(unsigned)kb[j];
  }
  __syncthreads();

  // ---- output: each part lane writes 2 neighbors (6 floats) ----
  float* o = out_knn + ((size_t)(b * NM + q)) * (NK * 3);
#pragma unroll
  for (int jj = 0; jj < 2; jj++) {
    const int j = part * 2 + jj;
    const int i = cand[ql * CAP + j];
    const int slot = (i >> 8) * CHUNK + (i & 255);
    o[3 * j + 0] = px[slot];
    o[3 * j + 1] = py[slot];
    o[3 * j + 2] = pz[slot];
  }
}

// ---------------------------------------------------------------------------
extern "C" void kernel_launch(void* const* d_in, const int* in_sizes, int n_in,
                              void* d_out, int out_size, void* d_ws,
                              size_t ws_size, hipStream_t stream) {
  const float* xyz      = (const float*)d_in[0];  // [8,2048,3]
  const float* xyz_fp   = (const float*)d_in[1];  // [8,8192,3]
  const float* features = (const float*)d_in[2];  // [8,64,2048]
  const float* W1 = (const float*)d_in[4];        // [64,64]
  const float* b1 = (const float*)d_in[5];        // [64]

  float* out_feats = (float*)d_out;                       // 8*2048*64
  float* out_knn   = out_feats + (size_t)NB * NN * NC;    // 8*8192*16*3
  float* out_x     = out_knn + (size_t)NB * NM * NK * 3;  // 8*2048*64

  fused_kernel<<<dim3(KB + FB, NB), 512, 0, stream>>>(
      features, W1, b1, out_feats, out_x, xyz, xyz_fp, out_knn);
}

// Round 9
// 209.103 us; speedup vs baseline: 1.0179x; 1.0179x over previous
//
#include <hip/hip_runtime.h>

#define NB 8
#define NN 2048
#define NM 8192
#define NC 64
#define ND 64
#define NK 16

#define PARTS 8     // lanes per query
#define PPT 256     // points per lane (NN / PARTS)
#define CHUNK 260   // padded chunk stride in floats: 260%32==4 -> parts on
                    // distinct bank-quads -> conflict-free ds_read_b128
#define QPB 64      // queries per block (512 threads / 8 parts)
#define NG 8        // groups of 32 points per lane
#define CAP 64      // candidate slots per query (overflow prob ~e^-40 + exact fallback)

#define KB (NM / QPB)       // knn blocks per batch (128) -- FIRST in grid
#define FB (NN / 64)        // feats blocks per batch (32) -- after knn
// knn LDS: 3*8*260*4 (24960) + 64*64*2 (8192) + 64*4 (256) = 33408 B
// -> 4 blocks/CU * 8 waves = 32 waves/CU IF VGPR<=64. launch_bounds(512,4)
// caps VGPR at 128 (compiler lands ~48, no spills -- r8's (512,8) cap=64
// forced 32 VGPR + scratch spills: FETCH 3.5->9.7MB, WRITE 20.5->33.9MB).
#define SMEM_BYTES 33408

__device__ __forceinline__ float d2rn(float qx, float qy, float qz, float x,
                                      float y, float z) {
  const float dx = __fsub_rn(qx, x);
  const float dy = __fsub_rn(qy, y);
  const float dz = __fsub_rn(qz, z);
  return __fadd_rn(__fadd_rn(__fmul_rn(dx, dx), __fmul_rn(dy, dy)),
                   __fmul_rn(dz, dz));
}

#define CE(a, i, j)                     \
  {                                     \
    const float lo = fminf(a[i], a[j]); \
    const float hi = fmaxf(a[i], a[j]); \
    a[i] = lo;                          \
    a[j] = hi;                          \
  }

// Batcher odd-even sort of d[8] ascending (19 comparators)
#define SORT8(d)                                  \
  CE(d, 0, 1) CE(d, 2, 3) CE(d, 4, 5) CE(d, 6, 7) \
  CE(d, 0, 2) CE(d, 1, 3) CE(d, 4, 6) CE(d, 5, 7) \
  CE(d, 1, 2) CE(d, 5, 6)                         \
  CE(d, 0, 4) CE(d, 1, 5) CE(d, 2, 6) CE(d, 3, 7) \
  CE(d, 2, 4) CE(d, 3, 5)                         \
  CE(d, 1, 2) CE(d, 3, 4) CE(d, 5, 6)

// bitonic sort of L[16] (input bitonic) ascending: 32 comparators
#define BITONIC16(L)                                                      \
  CE(L, 0, 8) CE(L, 1, 9) CE(L, 2, 10) CE(L, 3, 11) CE(L, 4, 12)          \
  CE(L, 5, 13) CE(L, 6, 14) CE(L, 7, 15)                                  \
  CE(L, 0, 4) CE(L, 1, 5) CE(L, 2, 6) CE(L, 3, 7) CE(L, 8, 12)            \
  CE(L, 9, 13) CE(L, 10, 14) CE(L, 11, 15)                                \
  CE(L, 0, 2) CE(L, 1, 3) CE(L, 4, 6) CE(L, 5, 7) CE(L, 8, 10)            \
  CE(L, 9, 11) CE(L, 12, 14) CE(L, 13, 15)                                \
  CE(L, 0, 1) CE(L, 2, 3) CE(L, 4, 5) CE(L, 6, 7) CE(L, 8, 9)             \
  CE(L, 10, 11) CE(L, 12, 13) CE(L, 14, 15)

__device__ __forceinline__ void dist8(const float* px, const float* py,
                                      const float* pz, int base, float qx,
                                      float qy, float qz, float d[8]) {
  const float4 X0 = *(const float4*)&px[base];
  const float4 X1 = *(const float4*)&px[base + 4];
  const float4 Y0 = *(const float4*)&py[base];
  const float4 Y1 = *(const float4*)&py[base + 4];
  const float4 Z0 = *(const float4*)&pz[base];
  const float4 Z1 = *(const float4*)&pz[base + 4];
  d[0] = d2rn(qx, qy, qz, X0.x, Y0.x, Z0.x);
  d[1] = d2rn(qx, qy, qz, X0.y, Y0.y, Z0.y);
  d[2] = d2rn(qx, qy, qz, X0.z, Y0.z, Z0.z);
  d[3] = d2rn(qx, qy, qz, X0.w, Y0.w, Z0.w);
  d[4] = d2rn(qx, qy, qz, X1.x, Y1.x, Z1.x);
  d[5] = d2rn(qx, qy, qz, X1.y, Y1.y, Z1.y);
  d[6] = d2rn(qx, qy, qz, X1.z, Y1.z, Z1.z);
  d[7] = d2rn(qx, qy, qz, X1.w, Y1.w, Z1.w);
}

__device__ __forceinline__ float min8(const float d[8]) {
  return fminf(fminf(fminf(d[0], d[1]), fminf(d[2], d[3])),
               fminf(fminf(d[4], d[5]), fminf(d[6], d[7])));
}

// ---------------------------------------------------------------------------
// Fused kernel, 512 threads: blockIdx.x < KB -> kNN (verbatim r2 per-thread
// algorithm, 8 waves/block); else -> feats/linear on t<256.
// ---------------------------------------------------------------------------
__global__ __launch_bounds__(512, 4) void fused_kernel(
    const float* __restrict__ features, const float* __restrict__ W1,
    const float* __restrict__ b1, float* __restrict__ out_feats,
    float* __restrict__ out_x, const float* __restrict__ xyz,
    const float* __restrict__ xyz_fp, float* __restrict__ out_knn) {
  __shared__ __align__(16) unsigned char smem[SMEM_BYTES];

  const int b = blockIdx.y;
  const int t = threadIdx.x;

  if (blockIdx.x >= KB) {
    // ============ feats + linear path (r7 body, threads 0..255) ============
    float(*tile)[68] = reinterpret_cast<float(*)[68]>(smem);  // 17408 B

    const int n0 = (blockIdx.x - KB) * 64;
    const int lane = t & 63;
    const int grp = (t >> 6) & 3;  // 0..3 for t<256

    if (t < 256) {
      for (int c = grp; c < NC; c += 4)
        tile[c][lane] = features[((size_t)(b * NC + c) * NN) + n0 + lane];
    }
    __syncthreads();
    if (t >= 256) return;

    // this thread's W1 row (w for d=lane, all c): 16 float4 in registers
    float4 wreg[16];
    {
      const float4* Wr = (const float4*)(W1 + lane * NC);
#pragma unroll
      for (int k = 0; k < 16; k++) wreg[k] = Wr[k];
    }

    for (int j = grp; j < 64; j += 4)
      out_feats[((size_t)(b * NN + n0 + j) * NC) + lane] = tile[lane][j];

    const int d = lane;
    float acc[16];
    const float bd = b1[d];
#pragma unroll
    for (int jj = 0; jj < 16; jj++) acc[jj] = bd;

    const float4* tv = (const float4*)&tile[0][0];
#pragma unroll
    for (int k = 0; k < 16; k++) {
#pragma unroll
      for (int cc = 0; cc < 4; cc++) {
        const int c = k * 4 + cc;
        const float w = (cc == 0)   ? wreg[k].x
                        : (cc == 1) ? wreg[k].y
                        : (cc == 2) ? wreg[k].z
                                    : wreg[k].w;
#pragma unroll
        for (int q = 0; q < 4; q++) {
          const float4 v = tv[c * 17 + grp * 4 + q];
          acc[q * 4 + 0] = fmaf(v.x, w, acc[q * 4 + 0]);
          acc[q * 4 + 1] = fmaf(v.y, w, acc[q * 4 + 1]);
          acc[q * 4 + 2] = fmaf(v.z, w, acc[q * 4 + 2]);
          acc[q * 4 + 3] = fmaf(v.w, w, acc[q * 4 + 3]);
        }
      }
    }
#pragma unroll
    for (int jj = 0; jj < 16; jj++) {
      const int j = grp * 16 + jj;
      out_x[((size_t)(b * NN + n0 + j) * ND) + d] = acc[jj];
    }
    return;
  }

  // ======================= kNN path (verbatim r2) =======================
  float* px = reinterpret_cast<float*>(smem);
  float* py = px + PARTS * CHUNK;
  float* pz = py + PARTS * CHUNK;
  unsigned short* cand =
      reinterpret_cast<unsigned short*>(smem + 3 * PARTS * CHUNK * 4);
  int* ccnt =
      reinterpret_cast<int*>(smem + 3 * PARTS * CHUNK * 4 + QPB * CAP * 2);

  const int ql = t >> 3;   // query-local 0..63
  const int part = t & 7;  // 0..7

  if (t < QPB) ccnt[t] = 0;

  // stage points SoA, chunked per part with +4 float pad
  const float* P = xyz + (size_t)b * NN * 3;
  for (int i = t; i < NN; i += 512) {
    const int slot = (i >> 8) * CHUNK + (i & 255);
    px[slot] = P[3 * i + 0];
    py[slot] = P[3 * i + 1];
    pz[slot] = P[3 * i + 2];
  }
  __syncthreads();

  const int q = blockIdx.x * QPB + ql;
  const float* Q = xyz_fp + ((size_t)b * NM + q) * 3;
  const float qx = Q[0], qy = Q[1], qz = Q[2];

  const int pbase = part * CHUNK;

  // ---- pass 1: group mins (8 groups of 32 points per lane) ----
  float gmin[NG];
#pragma unroll
  for (int g = 0; g < NG; g++) {
    float gm = 3.0e38f;
#pragma unroll
    for (int bb = 0; bb < 4; bb++) {
      float d[8];
      dist8(px, py, pz, pbase + g * 32 + bb * 8, qx, qy, qz, d);
      gm = fminf(gm, min8(d));
    }
    gmin[g] = gm;
  }

  // ---- T = 16th-smallest of the query's 64 group-mins ----
  float s[16];
  {
    float g8[NG];
#pragma unroll
    for (int g = 0; g < NG; g++) g8[g] = gmin[g];
    SORT8(g8)
#pragma unroll
    for (int j = 0; j < 8; j++) s[j] = g8[j];
#pragma unroll
    for (int j = 8; j < 16; j++) s[j] = 3.0e38f;
  }
#pragma unroll
  for (int mask = 1; mask <= 4; mask <<= 1) {
    float B[16];
#pragma unroll
    for (int j = 0; j < 16; j++) B[j] = __shfl_xor(s[j], mask, 64);
    float L[16];
#pragma unroll
    for (int j = 0; j < 16; j++) L[j] = fminf(s[j], B[15 - j]);
    BITONIC16(L)
#pragma unroll
    for (int j = 0; j < 16; j++) s[j] = L[j];
  }
  const float T = s[15];

  // ---- per-lane 8-bit pass mask ----
  unsigned m8 = 0;
#pragma unroll
  for (int g = 0; g < NG; g++) m8 |= (gmin[g] <= T) ? (1u << g) : 0u;

  // ---- butterfly-OR across the query's 8 lanes -> 64-bit group mask ----
  unsigned lo = (part < 4) ? (m8 << (8 * part)) : 0u;
  unsigned hi = (part >= 4) ? (m8 << (8 * (part - 4))) : 0u;
#pragma unroll
  for (int mk = 1; mk <= 4; mk <<= 1) {
    lo |= __shfl_xor(lo, mk, 64);
    hi |= __shfl_xor(hi, mk, 64);
  }
  const unsigned long long vm = ((unsigned long long)hi << 32) | lo;

  // ---- round-robin: k-th set bit -> lane (k & 7) ----
  unsigned long long mym = 0ull;
  {
    unsigned long long m = vm;
    int cnt = 0;
    while (m) {
      const unsigned long long lb = m & (0ull - m);
      if ((cnt & 7) == part) mym |= lb;
      m ^= lb;
      cnt++;
    }
  }

  // ---- pass 2: scan assigned groups (any chunk), collect candidates ----
  while (mym) {
    const int gid = __ffsll(mym) - 1;
    mym &= mym - 1;
    const int gb = (gid >> 3) * CHUNK + (gid & 7) * 32;
    const int ib = (gid >> 3) * PPT + (gid & 7) * 32;
#pragma unroll
    for (int bb = 0; bb < 4; bb++) {
      float d[8];
      dist8(px, py, pz, gb + bb * 8, qx, qy, qz, d);
      if (min8(d) <= T) {
#pragma unroll
        for (int j = 0; j < 8; j++) {
          if (d[j] <= T) {
            const int pos = atomicAdd(&ccnt[ql], 1);
            if (pos < CAP)
              cand[ql * CAP + pos] = (unsigned short)(ib + bb * 8 + j);
          }
        }
      }
    }
  }
  __syncthreads();

  // ---- phase 3: exact stable top-16 by (d2, idx) u64 keys ----
  if (part == 0) {
    const int cnt = ccnt[ql];
    unsigned long long kb[NK];
#pragma unroll
    for (int j = 0; j < NK; j++) kb[j] = ~0ULL;

    if (cnt <= CAP) {
      for (int c = 0; c < cnt; c++) {
        const int i = cand[ql * CAP + c];
        const int slot = (i >> 8) * CHUNK + (i & 255);
        const float d2 = d2rn(qx, qy, qz, px[slot], py[slot], pz[slot]);
        unsigned long long kk =
            ((unsigned long long)__float_as_uint(d2) << 32) | (unsigned)i;
        if (kk < kb[NK - 1]) {
#pragma unroll
          for (int j = 0; j < NK; j++) {
            const bool c2 = kk < kb[j];
            const unsigned long long lo2 = c2 ? kk : kb[j];
            const unsigned long long hi2 = c2 ? kb[j] : kk;
            kb[j] = lo2;
            kk = hi2;
          }
        }
      }
    } else {
      // overflow fallback (astronomically rare): exact scan of all points
      for (int i = 0; i < NN; i++) {
        const int slot = (i >> 8) * CHUNK + (i & 255);
        const float d2 = d2rn(qx, qy, qz, px[slot], py[slot], pz[slot]);
        unsigned long long kk =
            ((unsigned long long)__float_as_uint(d2) << 32) | (unsigned)i;
        if (kk < kb[NK - 1]) {
#pragma unroll
          for (int j = 0; j < NK; j++) {
            const bool c2 = kk < kb[j];
            const unsigned long long lo2 = c2 ? kk : kb[j];
            const unsigned long long hi2 = c2 ? kb[j] : kk;
            kb[j] = lo2;
            kk = hi2;
          }
        }
      }
    }
#pragma unroll
    for (int j = 0; j < NK; j++)
      cand[ql * CAP + j] = (unsigned short)(unsigned)kb[j];
  }
  __syncthreads();

  // ---- output: each part lane writes 2 neighbors (6 floats) ----
  float* o = out_knn + ((size_t)(b * NM + q)) * (NK * 3);
#pragma unroll
  for (int jj = 0; jj < 2; jj++) {
    const int j = part * 2 + jj;
    const int i = cand[ql * CAP + j];
    const int slot = (i >> 8) * CHUNK + (i & 255);
    o[3 * j + 0] = px[slot];
    o[3 * j + 1] = py[slot];
    o[3 * j + 2] = pz[slot];
  }
}

// ---------------------------------------------------------------------------
extern "C" void kernel_launch(void* const* d_in, const int* in_sizes, int n_in,
                              void* d_out, int out_size, void* d_ws,
                              size_t ws_size, hipStream_t stream) {
  const float* xyz      = (const float*)d_in[0];  // [8,2048,3]
  const float* xyz_fp   = (const float*)d_in[1];  // [8,8192,3]
  const float* features = (const float*)d_in[2];  // [8,64,2048]
  const float* W1 = (const float*)d_in[4];        // [64,64]
  const float* b1 = (const float*)d_in[5];        // [64]

  float* out_feats = (float*)d_out;                       // 8*2048*64
  float* out_knn   = out_feats + (size_t)NB * NN * NC;    // 8*8192*16*3
  float* out_x     = out_knn + (size_t)NB * NM * NK * 3;  // 8*2048*64

  fused_kernel<<<dim3(KB + FB, NB), 512, 0, stream>>>(
      features, W1, b1, out_feats, out_x, xyz, xyz_fp, out_knn);
}

// Round 10
// 186.665 us; speedup vs baseline: 1.1402x; 1.1202x over previous
//
#include <hip/hip_runtime.h>

#define NB 8
#define NN 2048
#define NM 8192
#define NC 64
#define ND 64
#define NK 16

#define PARTS 8     // lanes per query
#define PPT 256     // points per lane (NN / PARTS)
#define CHUNK 260   // padded chunk stride in floats: 260%32==4 -> parts on
                    // distinct bank-quads -> conflict-free ds_read_b128
#define QPB 32      // queries per block (256 threads / 8 parts)
#define NG 8        // groups of 32 points per lane
#define CAP 64      // candidate slots per query (overflow prob ~e^-40 + exact fallback)

#define KB (NM / QPB)       // knn blocks per batch (256) -- FIRST in grid
#define FB (NN / 64)        // feats blocks per batch (32) -- after knn
#define SMEM_BYTES 29184    // knn: 3*8*260*4 + 32*64*2 + 32*4 = 29184
                            // feats: tile only = 64*68*4 = 17408 (W in regs)
// NOTE r8/r9 lesson: 512-thread blocks regress ~17% even without spills
// (wider barrier domains); 256-thread 5-blocks/CU is the best measured.

typedef __attribute__((ext_vector_type(2))) float f2;
typedef __attribute__((ext_vector_type(4))) float f4;

__device__ __forceinline__ float d2rn(float qx, float qy, float qz, float x,
                                      float y, float z) {
  const float dx = __fsub_rn(qx, x);
  const float dy = __fsub_rn(qy, y);
  const float dz = __fsub_rn(qz, z);
  return __fadd_rn(__fadd_rn(__fmul_rn(dx, dx), __fmul_rn(dy, dy)),
                   __fmul_rn(dz, dz));
}

#define CE(a, i, j)                     \
  {                                     \
    const float lo = fminf(a[i], a[j]); \
    const float hi = fmaxf(a[i], a[j]); \
    a[i] = lo;                          \
    a[j] = hi;                          \
  }

// Batcher odd-even sort of d[8] ascending (19 comparators)
#define SORT8(d)                                  \
  CE(d, 0, 1) CE(d, 2, 3) CE(d, 4, 5) CE(d, 6, 7) \
  CE(d, 0, 2) CE(d, 1, 3) CE(d, 4, 6) CE(d, 5, 7) \
  CE(d, 1, 2) CE(d, 5, 6)                         \
  CE(d, 0, 4) CE(d, 1, 5) CE(d, 2, 6) CE(d, 3, 7) \
  CE(d, 2, 4) CE(d, 3, 5)                         \
  CE(d, 1, 2) CE(d, 3, 4) CE(d, 5, 6)

// bitonic sort of L[16] (input bitonic) ascending: 32 comparators
#define BITONIC16(L)                                                      \
  CE(L, 0, 8) CE(L, 1, 9) CE(L, 2, 10) CE(L, 3, 11) CE(L, 4, 12)          \
  CE(L, 5, 13) CE(L, 6, 14) CE(L, 7, 15)                                  \
  CE(L, 0, 4) CE(L, 1, 5) CE(L, 2, 6) CE(L, 3, 7) CE(L, 8, 12)            \
  CE(L, 9, 13) CE(L, 10, 14) CE(L, 11, 15)                                \
  CE(L, 0, 2) CE(L, 1, 3) CE(L, 4, 6) CE(L, 5, 7) CE(L, 8, 10)            \
  CE(L, 9, 11) CE(L, 12, 14) CE(L, 13, 15)                                \
  CE(L, 0, 1) CE(L, 2, 3) CE(L, 4, 5) CE(L, 6, 7) CE(L, 8, 9)             \
  CE(L, 10, 11) CE(L, 12, 13) CE(L, 14, 15)

// Packed-pair distance: 8 points -> 4 f2 of d^2. Uses <2 x float> arithmetic
// so LLVM can select v_pk_{add,mul}_f32 (gfx90a+ VOP3P): 2 points per issue.
// pk_mul/pk_add are bitwise == scalar _rn per half; contract(off) forbids
// FMA fusion -> d2 bits identical to d2rn's (selection order preserved).
__device__ __forceinline__ void dist8p(const float* px, const float* py,
                                       const float* pz, int base, float qx,
                                       float qy, float qz, f2 dd[4]) {
#pragma clang fp contract(off)
  const f4 X0 = *(const f4*)&px[base];
  const f4 X1 = *(const f4*)&px[base + 4];
  const f4 Y0 = *(const f4*)&py[base];
  const f4 Y1 = *(const f4*)&py[base + 4];
  const f4 Z0 = *(const f4*)&pz[base];
  const f4 Z1 = *(const f4*)&pz[base + 4];
  const f2 qvx = {qx, qx}, qvy = {qy, qy}, qvz = {qz, qz};
  {
    const f2 dx = qvx - X0.xy, dy = qvy - Y0.xy, dz = qvz - Z0.xy;
    dd[0] = (dx * dx + dy * dy) + dz * dz;
  }
  {
    const f2 dx = qvx - X0.zw, dy = qvy - Y0.zw, dz = qvz - Z0.zw;
    dd[1] = (dx * dx + dy * dy) + dz * dz;
  }
  {
    const f2 dx = qvx - X1.xy, dy = qvy - Y1.xy, dz = qvz - Z1.xy;
    dd[2] = (dx * dx + dy * dy) + dz * dz;
  }
  {
    const f2 dx = qvx - X1.zw, dy = qvy - Y1.zw, dz = qvz - Z1.zw;
    dd[3] = (dx * dx + dy * dy) + dz * dz;
  }
}

__device__ __forceinline__ float min8p(const f2 dd[4]) {
  return fminf(fminf(fminf(dd[0].x, dd[0].y), fminf(dd[1].x, dd[1].y)),
               fminf(fminf(dd[2].x, dd[2].y), fminf(dd[3].x, dd[3].y)));
}

// ---------------------------------------------------------------------------
// Fused kernel (r7 structure): blockIdx.x < KB -> kNN path; else feats path.
// Only change vs r7: distance core uses packed-pair dist8p.
// ---------------------------------------------------------------------------
__global__ __launch_bounds__(256, 4) void fused_kernel(
    const float* __restrict__ features, const float* __restrict__ W1,
    const float* __restrict__ b1, float* __restrict__ out_feats,
    float* __restrict__ out_x, const float* __restrict__ xyz,
    const float* __restrict__ xyz_fp, float* __restrict__ out_knn) {
  __shared__ __align__(16) unsigned char smem[SMEM_BYTES];

  const int b = blockIdx.y;
  const int t = threadIdx.x;

  if (blockIdx.x >= KB) {
    // ================= feats + linear path (verbatim r7) =================
    float(*tile)[68] = reinterpret_cast<float(*)[68]>(smem);  // 17408 B

    const int n0 = (blockIdx.x - KB) * 64;
    const int lane = t & 63;
    const int grp = t >> 6;

    for (int c = grp; c < NC; c += 4)
      tile[c][lane] = features[((size_t)(b * NC + c) * NN) + n0 + lane];

    // this thread's W1 row (w for d=lane, all c): 16 float4 in registers
    float4 wreg[16];
    {
      const float4* Wr = (const float4*)(W1 + lane * NC);
#pragma unroll
      for (int k = 0; k < 16; k++) wreg[k] = Wr[k];
    }
    __syncthreads();

    for (int j = grp; j < 64; j += 4)
      out_feats[((size_t)(b * NN + n0 + j) * NC) + lane] = tile[lane][j];

    const int d = lane;
    float acc[16];
    const float bd = b1[d];
#pragma unroll
    for (int jj = 0; jj < 16; jj++) acc[jj] = bd;

    const float4* tv = (const float4*)&tile[0][0];
#pragma unroll
    for (int k = 0; k < 16; k++) {
#pragma unroll
      for (int cc = 0; cc < 4; cc++) {
        const int c = k * 4 + cc;
        const float w = (cc == 0)   ? wreg[k].x
                        : (cc == 1) ? wreg[k].y
                        : (cc == 2) ? wreg[k].z
                                    : wreg[k].w;
#pragma unroll
        for (int q = 0; q < 4; q++) {
          const float4 v = tv[c * 17 + grp * 4 + q];
          acc[q * 4 + 0] = fmaf(v.x, w, acc[q * 4 + 0]);
          acc[q * 4 + 1] = fmaf(v.y, w, acc[q * 4 + 1]);
          acc[q * 4 + 2] = fmaf(v.z, w, acc[q * 4 + 2]);
          acc[q * 4 + 3] = fmaf(v.w, w, acc[q * 4 + 3]);
        }
      }
    }
#pragma unroll
    for (int jj = 0; jj < 16; jj++) {
      const int j = grp * 16 + jj;
      out_x[((size_t)(b * NN + n0 + j) * ND) + d] = acc[jj];
    }
    return;
  }

  // ======================= kNN path (r2 structure) =======================
  float* px = reinterpret_cast<float*>(smem);
  float* py = px + PARTS * CHUNK;
  float* pz = py + PARTS * CHUNK;
  unsigned short* cand =
      reinterpret_cast<unsigned short*>(smem + 3 * PARTS * CHUNK * 4);
  int* ccnt =
      reinterpret_cast<int*>(smem + 3 * PARTS * CHUNK * 4 + QPB * CAP * 2);

  const int ql = t >> 3;   // query-local 0..31
  const int part = t & 7;  // 0..7

  if (t < QPB) ccnt[t] = 0;

  // stage points SoA, chunked per part with +4 float pad
  const float* P = xyz + (size_t)b * NN * 3;
  for (int i = t; i < NN; i += 256) {
    const int slot = (i >> 8) * CHUNK + (i & 255);
    px[slot] = P[3 * i + 0];
    py[slot] = P[3 * i + 1];
    pz[slot] = P[3 * i + 2];
  }
  __syncthreads();

  const int q = blockIdx.x * QPB + ql;
  const float* Q = xyz_fp + ((size_t)b * NM + q) * 3;
  const float qx = Q[0], qy = Q[1], qz = Q[2];

  const int pbase = part * CHUNK;

  // ---- pass 1: group mins (8 groups of 32 points per lane) ----
  float gmin[NG];
#pragma unroll
  for (int g = 0; g < NG; g++) {
    float gm = 3.0e38f;
#pragma unroll
    for (int bb = 0; bb < 4; bb++) {
      f2 dd[4];
      dist8p(px, py, pz, pbase + g * 32 + bb * 8, qx, qy, qz, dd);
      gm = fminf(gm, min8p(dd));
    }
    gmin[g] = gm;
  }

  // ---- T = 16th-smallest of the query's 64 group-mins ----
  float s[16];
  {
    float g8[NG];
#pragma unroll
    for (int g = 0; g < NG; g++) g8[g] = gmin[g];
    SORT8(g8)
#pragma unroll
    for (int j = 0; j < 8; j++) s[j] = g8[j];
#pragma unroll
    for (int j = 8; j < 16; j++) s[j] = 3.0e38f;
  }
#pragma unroll
  for (int mask = 1; mask <= 4; mask <<= 1) {
    float B[16];
#pragma unroll
    for (int j = 0; j < 16; j++) B[j] = __shfl_xor(s[j], mask, 64);
    float L[16];
#pragma unroll
    for (int j = 0; j < 16; j++) L[j] = fminf(s[j], B[15 - j]);
    BITONIC16(L)
#pragma unroll
    for (int j = 0; j < 16; j++) s[j] = L[j];
  }
  const float T = s[15];

  // ---- per-lane 8-bit pass mask ----
  unsigned m8 = 0;
#pragma unroll
  for (int g = 0; g < NG; g++) m8 |= (gmin[g] <= T) ? (1u << g) : 0u;

  // ---- butterfly-OR across the query's 8 lanes -> 64-bit group mask ----
  unsigned lo = (part < 4) ? (m8 << (8 * part)) : 0u;
  unsigned hi = (part >= 4) ? (m8 << (8 * (part - 4))) : 0u;
#pragma unroll
  for (int mk = 1; mk <= 4; mk <<= 1) {
    lo |= __shfl_xor(lo, mk, 64);
    hi |= __shfl_xor(hi, mk, 64);
  }
  const unsigned long long vm = ((unsigned long long)hi << 32) | lo;

  // ---- round-robin: k-th set bit -> lane (k & 7) ----
  unsigned long long mym = 0ull;
  {
    unsigned long long m = vm;
    int cnt = 0;
    while (m) {
      const unsigned long long lb = m & (0ull - m);
      if ((cnt & 7) == part) mym |= lb;
      m ^= lb;
      cnt++;
    }
  }

  // ---- pass 2: scan assigned groups (any chunk), collect candidates ----
  while (mym) {
    const int gid = __ffsll(mym) - 1;
    mym &= mym - 1;
    const int gb = (gid >> 3) * CHUNK + (gid & 7) * 32;
    const int ib = (gid >> 3) * PPT + (gid & 7) * 32;
#pragma unroll
    for (int bb = 0; bb < 4; bb++) {
      f2 dd[4];
      dist8p(px, py, pz, gb + bb * 8, qx, qy, qz, dd);
      if (min8p(dd) <= T) {
#pragma unroll
        for (int k = 0; k < 4; k++) {
          if (dd[k].x <= T) {
            const int pos = atomicAdd(&ccnt[ql], 1);
            if (pos < CAP)
              cand[ql * CAP + pos] = (unsigned short)(ib + bb * 8 + 2 * k);
          }
          if (dd[k].y <= T) {
            const int pos = atomicAdd(&ccnt[ql], 1);
            if (pos < CAP)
              cand[ql * CAP + pos] = (unsigned short)(ib + bb * 8 + 2 * k + 1);
          }
        }
      }
    }
  }
  __syncthreads();

  // ---- phase 3: exact stable top-16 by (d2, idx) u64 keys ----
  if (part == 0) {
    const int cnt = ccnt[ql];
    unsigned long long kb[NK];
#pragma unroll
    for (int j = 0; j < NK; j++) kb[j] = ~0ULL;

    if (cnt <= CAP) {
      for (int c = 0; c < cnt; c++) {
        const int i = cand[ql * CAP + c];
        const int slot = (i >> 8) * CHUNK + (i & 255);
        const float d2 = d2rn(qx, qy, qz, px[slot], py[slot], pz[slot]);
        unsigned long long kk =
            ((unsigned long long)__float_as_uint(d2) << 32) | (unsigned)i;
        if (kk < kb[NK - 1]) {
#pragma unroll
          for (int j = 0; j < NK; j++) {
            const bool c2 = kk < kb[j];
            const unsigned long long lo2 = c2 ? kk : kb[j];
            const unsigned long long hi2 = c2 ? kb[j] : kk;
            kb[j] = lo2;
            kk = hi2;
          }
        }
      }
    } else {
      // overflow fallback (astronomically rare): exact scan of all points
      for (int i = 0; i < NN; i++) {
        const int slot = (i >> 8) * CHUNK + (i & 255);
        const float d2 = d2rn(qx, qy, qz, px[slot], py[slot], pz[slot]);
        unsigned long long kk =
            ((unsigned long long)__float_as_uint(d2) << 32) | (unsigned)i;
        if (kk < kb[NK - 1]) {
#pragma unroll
          for (int j = 0; j < NK; j++) {
            const bool c2 = kk < kb[j];
            const unsigned long long lo2 = c2 ? kk : kb[j];
            const unsigned long long hi2 = c2 ? kb[j] : kk;
            kb[j] = lo2;
            kk = hi2;
          }
        }
      }
    }
#pragma unroll
    for (int j = 0; j < NK; j++)
      cand[ql * CAP + j] = (unsigned short)(unsigned)kb[j];
  }
  __syncthreads();

  // ---- output: each part lane writes 2 neighbors (6 floats) ----
  float* o = out_knn + ((size_t)(b * NM + q)) * (NK * 3);
#pragma unroll
  for (int jj = 0; jj < 2; jj++) {
    const int j = part * 2 + jj;
    const int i = cand[ql * CAP + j];
    const int slot = (i >> 8) * CHUNK + (i & 255);
    o[3 * j + 0] = px[slot];
    o[3 * j + 1] = py[slot];
    o[3 * j + 2] = pz[slot];
  }
}

// ---------------------------------------------------------------------------
extern "C" void kernel_launch(void* const* d_in, const int* in_sizes, int n_in,
                              void* d_out, int out_size, void* d_ws,
                              size_t ws_size, hipStream_t stream) {
  const float* xyz      = (const float*)d_in[0];  // [8,2048,3]
  const float* xyz_fp   = (const float*)d_in[1];  // [8,8192,3]
  const float* features = (const float*)d_in[2];  // [8,64,2048]
  const float* W1 = (const float*)d_in[4];        // [64,64]
  const float* b1 = (const float*)d_in[5];        // [64]

  float* out_feats = (float*)d_out;                       // 8*2048*64
  float* out_knn   = out_feats + (size_t)NB * NN * NC;    // 8*8192*16*3
  float* out_x     = out_knn + (size_t)NB * NM * NK * 3;  // 8*2048*64

  fused_kernel<<<dim3(KB + FB, NB), 256, 0, stream>>>(
      features, W1, b1, out_feats, out_x, xyz, xyz_fp, out_knn);
}

// Round 11
// 142.376 us; speedup vs baseline: 1.4949x; 1.3111x over previous
//
#include <hip/hip_runtime.h>

#define NB 8
#define NN 2048
#define NM 8192
#define NC 64
#define ND 64
#define NK 16

#define PARTS 8     // lanes per query
#define PPT 256     // points per lane (NN / PARTS)
#define CHUNK 260   // padded chunk stride in floats: 260%32==4 -> parts on
                    // distinct bank-quads -> conflict-free ds_read_b128
#define QPB 32      // queries per block (256 threads / 8 parts)
#define NG 8        // groups of 32 points per lane
#define CAP 64      // candidate slots per query (overflow prob ~e^-40 + exact fallback)

#define KB (NM / QPB)       // knn blocks per batch (256) -- FIRST in grid
#define FB (NN / 64)        // feats blocks per batch (32) -- after knn
#define SMEM_BYTES 29184    // knn: 3*8*260*4 + 32*64*2 + 32*4 = 29184
                            // feats: tile only = 64*68*4 = 17408 (W in regs)
// r8/r9 lesson: 512-thread blocks regress ~17% even without spills.
// r10 lesson: packed dist8p cut VALU issue (VALUBusy 64->56) but time flat
// -> phase-3 serial u64 insertion dominates wave issue; parallelized here.

typedef __attribute__((ext_vector_type(2))) float f2;
typedef __attribute__((ext_vector_type(4))) float f4;

__device__ __forceinline__ float d2rn(float qx, float qy, float qz, float x,
                                      float y, float z) {
  const float dx = __fsub_rn(qx, x);
  const float dy = __fsub_rn(qy, y);
  const float dz = __fsub_rn(qz, z);
  return __fadd_rn(__fadd_rn(__fmul_rn(dx, dx), __fmul_rn(dy, dy)),
                   __fmul_rn(dz, dz));
}

#define CE(a, i, j)                     \
  {                                     \
    const float lo = fminf(a[i], a[j]); \
    const float hi = fmaxf(a[i], a[j]); \
    a[i] = lo;                          \
    a[j] = hi;                          \
  }

// u64 compare-exchange (ascending)
#define CEU(a, i, j)                                      \
  {                                                       \
    const bool c_ = a[i] < a[j];                          \
    const unsigned long long lo_ = c_ ? a[i] : a[j];      \
    const unsigned long long hi_ = c_ ? a[j] : a[i];      \
    a[i] = lo_;                                           \
    a[j] = hi_;                                           \
  }

// Batcher odd-even sort of d[8] ascending (19 comparators) -- float
#define SORT8(d)                                  \
  CE(d, 0, 1) CE(d, 2, 3) CE(d, 4, 5) CE(d, 6, 7) \
  CE(d, 0, 2) CE(d, 1, 3) CE(d, 4, 6) CE(d, 5, 7) \
  CE(d, 1, 2) CE(d, 5, 6)                         \
  CE(d, 0, 4) CE(d, 1, 5) CE(d, 2, 6) CE(d, 3, 7) \
  CE(d, 2, 4) CE(d, 3, 5)                         \
  CE(d, 1, 2) CE(d, 3, 4) CE(d, 5, 6)

// Batcher odd-even sort of u64[8] ascending (19 comparators)
#define SORT8U(d)                                          \
  CEU(d, 0, 1) CEU(d, 2, 3) CEU(d, 4, 5) CEU(d, 6, 7)      \
  CEU(d, 0, 2) CEU(d, 1, 3) CEU(d, 4, 6) CEU(d, 5, 7)      \
  CEU(d, 1, 2) CEU(d, 5, 6)                                \
  CEU(d, 0, 4) CEU(d, 1, 5) CEU(d, 2, 6) CEU(d, 3, 7)      \
  CEU(d, 2, 4) CEU(d, 3, 5)                                \
  CEU(d, 1, 2) CEU(d, 3, 4) CEU(d, 5, 6)

// bitonic-8 sorter (input must be bitonic) -- u64, 12 comparators
#define BSORT8U(d)                                         \
  CEU(d, 0, 4) CEU(d, 1, 5) CEU(d, 2, 6) CEU(d, 3, 7)      \
  CEU(d, 0, 2) CEU(d, 1, 3) CEU(d, 4, 6) CEU(d, 5, 7)      \
  CEU(d, 0, 1) CEU(d, 2, 3) CEU(d, 4, 5) CEU(d, 6, 7)

// bitonic sort of L[16] (input bitonic) ascending: 32 comparators -- float
#define BITONIC16(L)                                                      \
  CE(L, 0, 8) CE(L, 1, 9) CE(L, 2, 10) CE(L, 3, 11) CE(L, 4, 12)          \
  CE(L, 5, 13) CE(L, 6, 14) CE(L, 7, 15)                                  \
  CE(L, 0, 4) CE(L, 1, 5) CE(L, 2, 6) CE(L, 3, 7) CE(L, 8, 12)            \
  CE(L, 9, 13) CE(L, 10, 14) CE(L, 11, 15)                                \
  CE(L, 0, 2) CE(L, 1, 3) CE(L, 4, 6) CE(L, 5, 7) CE(L, 8, 10)            \
  CE(L, 9, 11) CE(L, 12, 14) CE(L, 13, 15)                                \
  CE(L, 0, 1) CE(L, 2, 3) CE(L, 4, 5) CE(L, 6, 7) CE(L, 8, 9)             \
  CE(L, 10, 11) CE(L, 12, 13) CE(L, 14, 15)

// Packed-pair distance: 8 points -> 4 f2 of d^2 (v_pk_* eligible; bitwise
// identical to scalar _rn per half; contract(off) forbids FMA fusion).
__device__ __forceinline__ void dist8p(const float* px, const float* py,
                                       const float* pz, int base, float qx,
                                       float qy, float qz, f2 dd[4]) {
#pragma clang fp contract(off)
  const f4 X0 = *(const f4*)&px[base];
  const f4 X1 = *(const f4*)&px[base + 4];
  const f4 Y0 = *(const f4*)&py[base];
  const f4 Y1 = *(const f4*)&py[base + 4];
  const f4 Z0 = *(const f4*)&pz[base];
  const f4 Z1 = *(const f4*)&pz[base + 4];
  const f2 qvx = {qx, qx}, qvy = {qy, qy}, qvz = {qz, qz};
  {
    const f2 dx = qvx - X0.xy, dy = qvy - Y0.xy, dz = qvz - Z0.xy;
    dd[0] = (dx * dx + dy * dy) + dz * dz;
  }
  {
    const f2 dx = qvx - X0.zw, dy = qvy - Y0.zw, dz = qvz - Z0.zw;
    dd[1] = (dx * dx + dy * dy) + dz * dz;
  }
  {
    const f2 dx = qvx - X1.xy, dy = qvy - Y1.xy, dz = qvz - Z1.xy;
    dd[2] = (dx * dx + dy * dy) + dz * dz;
  }
  {
    const f2 dx = qvx - X1.zw, dy = qvy - Y1.zw, dz = qvz - Z1.zw;
    dd[3] = (dx * dx + dy * dy) + dz * dz;
  }
}

__device__ __forceinline__ float min8p(const f2 dd[4]) {
  return fminf(fminf(fminf(dd[0].x, dd[0].y), fminf(dd[1].x, dd[1].y)),
               fminf(fminf(dd[2].x, dd[2].y), fminf(dd[3].x, dd[3].y)));
}

// ---------------------------------------------------------------------------
// Fused kernel (r10 structure); only phase 3 changed: 8-lane parallel exact
// top-16 via local Batcher sort + 3 bitonic shfl-merge rounds.
// ---------------------------------------------------------------------------
__global__ __launch_bounds__(256, 4) void fused_kernel(
    const float* __restrict__ features, const float* __restrict__ W1,
    const float* __restrict__ b1, float* __restrict__ out_feats,
    float* __restrict__ out_x, const float* __restrict__ xyz,
    const float* __restrict__ xyz_fp, float* __restrict__ out_knn) {
  __shared__ __align__(16) unsigned char smem[SMEM_BYTES];

  const int b = blockIdx.y;
  const int t = threadIdx.x;

  if (blockIdx.x >= KB) {
    // ================= feats + linear path (verbatim r7) =================
    float(*tile)[68] = reinterpret_cast<float(*)[68]>(smem);  // 17408 B

    const int n0 = (blockIdx.x - KB) * 64;
    const int lane = t & 63;
    const int grp = t >> 6;

    for (int c = grp; c < NC; c += 4)
      tile[c][lane] = features[((size_t)(b * NC + c) * NN) + n0 + lane];

    float4 wreg[16];
    {
      const float4* Wr = (const float4*)(W1 + lane * NC);
#pragma unroll
      for (int k = 0; k < 16; k++) wreg[k] = Wr[k];
    }
    __syncthreads();

    for (int j = grp; j < 64; j += 4)
      out_feats[((size_t)(b * NN + n0 + j) * NC) + lane] = tile[lane][j];

    const int d = lane;
    float acc[16];
    const float bd = b1[d];
#pragma unroll
    for (int jj = 0; jj < 16; jj++) acc[jj] = bd;

    const float4* tv = (const float4*)&tile[0][0];
#pragma unroll
    for (int k = 0; k < 16; k++) {
#pragma unroll
      for (int cc = 0; cc < 4; cc++) {
        const int c = k * 4 + cc;
        const float w = (cc == 0)   ? wreg[k].x
                        : (cc == 1) ? wreg[k].y
                        : (cc == 2) ? wreg[k].z
                                    : wreg[k].w;
#pragma unroll
        for (int q = 0; q < 4; q++) {
          const float4 v = tv[c * 17 + grp * 4 + q];
          acc[q * 4 + 0] = fmaf(v.x, w, acc[q * 4 + 0]);
          acc[q * 4 + 1] = fmaf(v.y, w, acc[q * 4 + 1]);
          acc[q * 4 + 2] = fmaf(v.z, w, acc[q * 4 + 2]);
          acc[q * 4 + 3] = fmaf(v.w, w, acc[q * 4 + 3]);
        }
      }
    }
#pragma unroll
    for (int jj = 0; jj < 16; jj++) {
      const int j = grp * 16 + jj;
      out_x[((size_t)(b * NN + n0 + j) * ND) + d] = acc[jj];
    }
    return;
  }

  // ======================= kNN path (r2 structure) =======================
  float* px = reinterpret_cast<float*>(smem);
  float* py = px + PARTS * CHUNK;
  float* pz = py + PARTS * CHUNK;
  unsigned short* cand =
      reinterpret_cast<unsigned short*>(smem + 3 * PARTS * CHUNK * 4);
  int* ccnt =
      reinterpret_cast<int*>(smem + 3 * PARTS * CHUNK * 4 + QPB * CAP * 2);

  const int ql = t >> 3;   // query-local 0..31
  const int part = t & 7;  // 0..7

  if (t < QPB) ccnt[t] = 0;

  // stage points SoA, chunked per part with +4 float pad
  const float* P = xyz + (size_t)b * NN * 3;
  for (int i = t; i < NN; i += 256) {
    const int slot = (i >> 8) * CHUNK + (i & 255);
    px[slot] = P[3 * i + 0];
    py[slot] = P[3 * i + 1];
    pz[slot] = P[3 * i + 2];
  }
  __syncthreads();

  const int q = blockIdx.x * QPB + ql;
  const float* Q = xyz_fp + ((size_t)b * NM + q) * 3;
  const float qx = Q[0], qy = Q[1], qz = Q[2];

  const int pbase = part * CHUNK;

  // ---- pass 1: group mins (8 groups of 32 points per lane) ----
  float gmin[NG];
#pragma unroll
  for (int g = 0; g < NG; g++) {
    float gm = 3.0e38f;
#pragma unroll
    for (int bb = 0; bb < 4; bb++) {
      f2 dd[4];
      dist8p(px, py, pz, pbase + g * 32 + bb * 8, qx, qy, qz, dd);
      gm = fminf(gm, min8p(dd));
    }
    gmin[g] = gm;
  }

  // ---- T = 16th-smallest of the query's 64 group-mins ----
  float s[16];
  {
    float g8[NG];
#pragma unroll
    for (int g = 0; g < NG; g++) g8[g] = gmin[g];
    SORT8(g8)
#pragma unroll
    for (int j = 0; j < 8; j++) s[j] = g8[j];
#pragma unroll
    for (int j = 8; j < 16; j++) s[j] = 3.0e38f;
  }
#pragma unroll
  for (int mask = 1; mask <= 4; mask <<= 1) {
    float B[16];
#pragma unroll
    for (int j = 0; j < 16; j++) B[j] = __shfl_xor(s[j], mask, 64);
    float L[16];
#pragma unroll
    for (int j = 0; j < 16; j++) L[j] = fminf(s[j], B[15 - j]);
    BITONIC16(L)
#pragma unroll
    for (int j = 0; j < 16; j++) s[j] = L[j];
  }
  const float T = s[15];

  // ---- per-lane 8-bit pass mask ----
  unsigned m8 = 0;
#pragma unroll
  for (int g = 0; g < NG; g++) m8 |= (gmin[g] <= T) ? (1u << g) : 0u;

  // ---- butterfly-OR across the query's 8 lanes -> 64-bit group mask ----
  unsigned lo = (part < 4) ? (m8 << (8 * part)) : 0u;
  unsigned hi = (part >= 4) ? (m8 << (8 * (part - 4))) : 0u;
#pragma unroll
  for (int mk = 1; mk <= 4; mk <<= 1) {
    lo |= __shfl_xor(lo, mk, 64);
    hi |= __shfl_xor(hi, mk, 64);
  }
  const unsigned long long vm = ((unsigned long long)hi << 32) | lo;

  // ---- round-robin: k-th set bit -> lane (k & 7) ----
  unsigned long long mym = 0ull;
  {
    unsigned long long m = vm;
    int cnt = 0;
    while (m) {
      const unsigned long long lb = m & (0ull - m);
      if ((cnt & 7) == part) mym |= lb;
      m ^= lb;
      cnt++;
    }
  }

  // ---- pass 2: scan assigned groups (any chunk), collect candidates ----
  while (mym) {
    const int gid = __ffsll(mym) - 1;
    mym &= mym - 1;
    const int gb = (gid >> 3) * CHUNK + (gid & 7) * 32;
    const int ib = (gid >> 3) * PPT + (gid & 7) * 32;
#pragma unroll
    for (int bb = 0; bb < 4; bb++) {
      f2 dd[4];
      dist8p(px, py, pz, gb + bb * 8, qx, qy, qz, dd);
      if (min8p(dd) <= T) {
#pragma unroll
        for (int k = 0; k < 4; k++) {
          if (dd[k].x <= T) {
            const int pos = atomicAdd(&ccnt[ql], 1);
            if (pos < CAP)
              cand[ql * CAP + pos] = (unsigned short)(ib + bb * 8 + 2 * k);
          }
          if (dd[k].y <= T) {
            const int pos = atomicAdd(&ccnt[ql], 1);
            if (pos < CAP)
              cand[ql * CAP + pos] = (unsigned short)(ib + bb * 8 + 2 * k + 1);
          }
        }
      }
    }
  }
  __syncthreads();

  // ---- phase 3: exact top-16, 8-lane parallel (local sort + bitonic
  //      shfl merges). Keys unique -> order bit-identical to serial. ----
  {
    const int cnt = ccnt[ql];
    if (cnt <= CAP) {
      unsigned long long kb8[8];
      // gather this lane's strided candidates: part, part+8, ...
#pragma unroll
      for (int i = 0; i < 8; i++) {
        const int c = part + 8 * i;
        unsigned long long kk = ~0ULL;
        if (c < cnt) {
          const int idx = cand[ql * CAP + c];
          const int slot = (idx >> 8) * CHUNK + (idx & 255);
          const float d2 = d2rn(qx, qy, qz, px[slot], py[slot], pz[slot]);
          kk = ((unsigned long long)__float_as_uint(d2) << 32) | (unsigned)idx;
        }
        kb8[i] = kk;
      }
      SORT8U(kb8)

      // round 1 (XOR 1): pair merge -> sorted-16 per lane pair
      //   even lane keeps low-8, odd lane keeps high-8
      {
        unsigned long long bb[8];
#pragma unroll
        for (int j = 0; j < 8; j++) bb[j] = __shfl_xor(kb8[7 - j], 1, 64);
        if (part & 1) {
#pragma unroll
          for (int j = 0; j < 8; j++)
            kb8[j] = (kb8[j] < bb[j]) ? bb[j] : kb8[j];
        } else {
#pragma unroll
          for (int j = 0; j < 8; j++)
            kb8[j] = (kb8[j] < bb[j]) ? kb8[j] : bb[j];
        }
        BSORT8U(kb8)
      }

      // rounds 2,3 (XOR 3 then XOR 5): merge two sorted-16s, keep top-16
      //   C[i]=min(A[i],B[15-i]) -> bitonic-16 -> cross-CE(XOR 1) + local sort
#pragma unroll
      for (int r = 0; r < 2; r++) {
        const int xm = r ? 5 : 3;
        unsigned long long bb[8];
#pragma unroll
        for (int j = 0; j < 8; j++) bb[j] = __shfl_xor(kb8[7 - j], xm, 64);
#pragma unroll
        for (int j = 0; j < 8; j++)
          kb8[j] = (kb8[j] < bb[j]) ? kb8[j] : bb[j];
#pragma unroll
        for (int j = 0; j < 8; j++) bb[j] = __shfl_xor(kb8[j], 1, 64);
        if (part & 1) {
#pragma unroll
          for (int j = 0; j < 8; j++)
            kb8[j] = (kb8[j] < bb[j]) ? bb[j] : kb8[j];
        } else {
#pragma unroll
          for (int j = 0; j < 8; j++)
            kb8[j] = (kb8[j] < bb[j]) ? kb8[j] : bb[j];
        }
        BSORT8U(kb8)
      }

      // final sorted-16: even lane holds ranks 0-7, odd lane ranks 8-15
      if (part < 2) {
#pragma unroll
        for (int j = 0; j < 8; j++)
          cand[ql * CAP + part * 8 + j] = (unsigned short)(unsigned)kb8[j];
      }
    } else if (part == 0) {
      // overflow fallback (astronomically rare): serial exact scan
      unsigned long long kb[NK];
#pragma unroll
      for (int j = 0; j < NK; j++) kb[j] = ~0ULL;
      for (int i = 0; i < NN; i++) {
        const int slot = (i >> 8) * CHUNK + (i & 255);
        const float d2 = d2rn(qx, qy, qz, px[slot], py[slot], pz[slot]);
        unsigned long long kk =
            ((unsigned long long)__float_as_uint(d2) << 32) | (unsigned)i;
        if (kk < kb[NK - 1]) {
#pragma unroll
          for (int j = 0; j < NK; j++) {
            const bool c2 = kk < kb[j];
            const unsigned long long lo2 = c2 ? kk : kb[j];
            const unsigned long long hi2 = c2 ? kb[j] : kk;
            kb[j] = lo2;
            kk = hi2;
          }
        }
      }
#pragma unroll
      for (int j = 0; j < NK; j++)
        cand[ql * CAP + j] = (unsigned short)(unsigned)kb[j];
    }
  }
  __syncthreads();

  // ---- output: each part lane writes 2 neighbors (6 floats) ----
  float* o = out_knn + ((size_t)(b * NM + q)) * (NK * 3);
#pragma unroll
  for (int jj = 0; jj < 2; jj++) {
    const int j = part * 2 + jj;
    const int i = cand[ql * CAP + j];
    const int slot = (i >> 8) * CHUNK + (i & 255);
    o[3 * j + 0] = px[slot];
    o[3 * j + 1] = py[slot];
    o[3 * j + 2] = pz[slot];
  }
}

// ---------------------------------------------------------------------------
extern "C" void kernel_launch(void* const* d_in, const int* in_sizes, int n_in,
                              void* d_out, int out_size, void* d_ws,
                              size_t ws_size, hipStream_t stream) {
  const float* xyz      = (const float*)d_in[0];  // [8,2048,3]
  const float* xyz_fp   = (const float*)d_in[1];  // [8,8192,3]
  const float* features = (const float*)d_in[2];  // [8,64,2048]
  const float* W1 = (const float*)d_in[4];        // [64,64]
  const float* b1 = (const float*)d_in[5];        // [64]

  float* out_feats = (float*)d_out;                       // 8*2048*64
  float* out_knn   = out_feats + (size_t)NB * NN * NC;    // 8*8192*16*3
  float* out_x     = out_knn + (size_t)NB * NM * NK * 3;  // 8*2048*64

  fused_kernel<<<dim3(KB + FB, NB), 256, 0, stream>>>(
      features, W1, b1, out_feats, out_x, xyz, xyz_fp, out_knn);
}

// Round 12
// 138.787 us; speedup vs baseline: 1.5336x; 1.0259x over previous
//
#include <hip/hip_runtime.h>

#define NB 8
#define NN 2048
#define NM 8192
#define NC 64
#define ND 64
#define NK 16

#define PARTS 8     // lanes per query
#define PPT 256     // points per lane (NN / PARTS)
#define CHUNK 260   // padded chunk stride in floats: 260%32==4 -> parts on
                    // distinct bank-quads -> conflict-free ds_read_b128
#define QPB 32      // queries per block (256 threads / 8 parts)
#define NG 8        // groups of 32 points per lane
#define CAP 64      // candidate slots per query (overflow prob ~e^-40 + exact fallback)
#define CSTR 66     // cand row stride in u16 (132 B, not mult of 128 B ->
                    // phase-3 strided gathers hit distinct banks per slot)

#define KB (NM / QPB)       // knn blocks per batch (256) -- FIRST in grid
#define FB (NN / 64)        // feats blocks per batch (32) -- after knn
#define SMEM_BYTES 29312    // knn: 3*8*260*4 + 32*66*2 + 32*4 = 29312 (5/CU)
                            // feats: tile only = 64*68*4 = 17408 (W in regs)
// r8/r9: 512-thread blocks regress ~17% even without spills.
// r10: packed dist8p freed VALU (64->56%) but time flat.
// r11: 8-lane-parallel phase 3 was the real long pole: 120 -> 73.5 us.

typedef __attribute__((ext_vector_type(2))) float f2;
typedef __attribute__((ext_vector_type(4))) float f4;

__device__ __forceinline__ float d2rn(float qx, float qy, float qz, float x,
                                      float y, float z) {
  const float dx = __fsub_rn(qx, x);
  const float dy = __fsub_rn(qy, y);
  const float dz = __fsub_rn(qz, z);
  return __fadd_rn(__fadd_rn(__fmul_rn(dx, dx), __fmul_rn(dy, dy)),
                   __fmul_rn(dz, dz));
}

#define CE(a, i, j)                     \
  {                                     \
    const float lo = fminf(a[i], a[j]); \
    const float hi = fmaxf(a[i], a[j]); \
    a[i] = lo;                          \
    a[j] = hi;                          \
  }

// u64 compare-exchange (ascending)
#define CEU(a, i, j)                                      \
  {                                                       \
    const bool c_ = a[i] < a[j];                          \
    const unsigned long long lo_ = c_ ? a[i] : a[j];      \
    const unsigned long long hi_ = c_ ? a[j] : a[i];      \
    a[i] = lo_;                                           \
    a[j] = hi_;                                           \
  }

// Batcher odd-even sort of d[8] ascending (19 comparators) -- float
#define SORT8(d)                                  \
  CE(d, 0, 1) CE(d, 2, 3) CE(d, 4, 5) CE(d, 6, 7) \
  CE(d, 0, 2) CE(d, 1, 3) CE(d, 4, 6) CE(d, 5, 7) \
  CE(d, 1, 2) CE(d, 5, 6)                         \
  CE(d, 0, 4) CE(d, 1, 5) CE(d, 2, 6) CE(d, 3, 7) \
  CE(d, 2, 4) CE(d, 3, 5)                         \
  CE(d, 1, 2) CE(d, 3, 4) CE(d, 5, 6)

// Batcher odd-even sort of u64[8] ascending (19 comparators)
#define SORT8U(d)                                          \
  CEU(d, 0, 1) CEU(d, 2, 3) CEU(d, 4, 5) CEU(d, 6, 7)      \
  CEU(d, 0, 2) CEU(d, 1, 3) CEU(d, 4, 6) CEU(d, 5, 7)      \
  CEU(d, 1, 2) CEU(d, 5, 6)                                \
  CEU(d, 0, 4) CEU(d, 1, 5) CEU(d, 2, 6) CEU(d, 3, 7)      \
  CEU(d, 2, 4) CEU(d, 3, 5)                                \
  CEU(d, 1, 2) CEU(d, 3, 4) CEU(d, 5, 6)

// bitonic-8 sorter (input must be bitonic) -- u64, 12 comparators
#define BSORT8U(d)                                         \
  CEU(d, 0, 4) CEU(d, 1, 5) CEU(d, 2, 6) CEU(d, 3, 7)      \
  CEU(d, 0, 2) CEU(d, 1, 3) CEU(d, 4, 6) CEU(d, 5, 7)      \
  CEU(d, 0, 1) CEU(d, 2, 3) CEU(d, 4, 5) CEU(d, 6, 7)

// bitonic sort of L[16] (input bitonic) ascending: 32 comparators -- float
#define BITONIC16(L)                                                      \
  CE(L, 0, 8) CE(L, 1, 9) CE(L, 2, 10) CE(L, 3, 11) CE(L, 4, 12)          \
  CE(L, 5, 13) CE(L, 6, 14) CE(L, 7, 15)                                  \
  CE(L, 0, 4) CE(L, 1, 5) CE(L, 2, 6) CE(L, 3, 7) CE(L, 8, 12)            \
  CE(L, 9, 13) CE(L, 10, 14) CE(L, 11, 15)                                \
  CE(L, 0, 2) CE(L, 1, 3) CE(L, 4, 6) CE(L, 5, 7) CE(L, 8, 10)            \
  CE(L, 9, 11) CE(L, 12, 14) CE(L, 13, 15)                                \
  CE(L, 0, 1) CE(L, 2, 3) CE(L, 4, 5) CE(L, 6, 7) CE(L, 8, 9)             \
  CE(L, 10, 11) CE(L, 12, 13) CE(L, 14, 15)

// Packed-pair distance: 8 points -> 4 f2 of d^2 (v_pk_* eligible; bitwise
// identical to scalar _rn per half; contract(off) forbids FMA fusion).
__device__ __forceinline__ void dist8p(const float* px, const float* py,
                                       const float* pz, int base, float qx,
                                       float qy, float qz, f2 dd[4]) {
#pragma clang fp contract(off)
  const f4 X0 = *(const f4*)&px[base];
  const f4 X1 = *(const f4*)&px[base + 4];
  const f4 Y0 = *(const f4*)&py[base];
  const f4 Y1 = *(const f4*)&py[base + 4];
  const f4 Z0 = *(const f4*)&pz[base];
  const f4 Z1 = *(const f4*)&pz[base + 4];
  const f2 qvx = {qx, qx}, qvy = {qy, qy}, qvz = {qz, qz};
  {
    const f2 dx = qvx - X0.xy, dy = qvy - Y0.xy, dz = qvz - Z0.xy;
    dd[0] = (dx * dx + dy * dy) + dz * dz;
  }
  {
    const f2 dx = qvx - X0.zw, dy = qvy - Y0.zw, dz = qvz - Z0.zw;
    dd[1] = (dx * dx + dy * dy) + dz * dz;
  }
  {
    const f2 dx = qvx - X1.xy, dy = qvy - Y1.xy, dz = qvz - Z1.xy;
    dd[2] = (dx * dx + dy * dy) + dz * dz;
  }
  {
    const f2 dx = qvx - X1.zw, dy = qvy - Y1.zw, dz = qvz - Z1.zw;
    dd[3] = (dx * dx + dy * dy) + dz * dz;
  }
}

__device__ __forceinline__ float min8p(const f2 dd[4]) {
  return fminf(fminf(fminf(dd[0].x, dd[0].y), fminf(dd[1].x, dd[1].y)),
               fminf(fminf(dd[2].x, dd[2].y), fminf(dd[3].x, dd[3].y)));
}

// ---------------------------------------------------------------------------
// Fused kernel (r11 structure); deltas: cand row stride 66 (bank-conflict
// fix) + batched pass-2 candidate reservation (1 atomic per accept-block).
// ---------------------------------------------------------------------------
__global__ __launch_bounds__(256, 4) void fused_kernel(
    const float* __restrict__ features, const float* __restrict__ W1,
    const float* __restrict__ b1, float* __restrict__ out_feats,
    float* __restrict__ out_x, const float* __restrict__ xyz,
    const float* __restrict__ xyz_fp, float* __restrict__ out_knn) {
  __shared__ __align__(16) unsigned char smem[SMEM_BYTES];

  const int b = blockIdx.y;
  const int t = threadIdx.x;

  if (blockIdx.x >= KB) {
    // ================= feats + linear path (verbatim r7) =================
    float(*tile)[68] = reinterpret_cast<float(*)[68]>(smem);  // 17408 B

    const int n0 = (blockIdx.x - KB) * 64;
    const int lane = t & 63;
    const int grp = t >> 6;

    for (int c = grp; c < NC; c += 4)
      tile[c][lane] = features[((size_t)(b * NC + c) * NN) + n0 + lane];

    float4 wreg[16];
    {
      const float4* Wr = (const float4*)(W1 + lane * NC);
#pragma unroll
      for (int k = 0; k < 16; k++) wreg[k] = Wr[k];
    }
    __syncthreads();

    for (int j = grp; j < 64; j += 4)
      out_feats[((size_t)(b * NN + n0 + j) * NC) + lane] = tile[lane][j];

    const int d = lane;
    float acc[16];
    const float bd = b1[d];
#pragma unroll
    for (int jj = 0; jj < 16; jj++) acc[jj] = bd;

    const float4* tv = (const float4*)&tile[0][0];
#pragma unroll
    for (int k = 0; k < 16; k++) {
#pragma unroll
      for (int cc = 0; cc < 4; cc++) {
        const int c = k * 4 + cc;
        const float w = (cc == 0)   ? wreg[k].x
                        : (cc == 1) ? wreg[k].y
                        : (cc == 2) ? wreg[k].z
                                    : wreg[k].w;
#pragma unroll
        for (int q = 0; q < 4; q++) {
          const float4 v = tv[c * 17 + grp * 4 + q];
          acc[q * 4 + 0] = fmaf(v.x, w, acc[q * 4 + 0]);
          acc[q * 4 + 1] = fmaf(v.y, w, acc[q * 4 + 1]);
          acc[q * 4 + 2] = fmaf(v.z, w, acc[q * 4 + 2]);
          acc[q * 4 + 3] = fmaf(v.w, w, acc[q * 4 + 3]);
        }
      }
    }
#pragma unroll
    for (int jj = 0; jj < 16; jj++) {
      const int j = grp * 16 + jj;
      out_x[((size_t)(b * NN + n0 + j) * ND) + d] = acc[jj];
    }
    return;
  }

  // ======================= kNN path (r2 structure) =======================
  float* px = reinterpret_cast<float*>(smem);
  float* py = px + PARTS * CHUNK;
  float* pz = py + PARTS * CHUNK;
  unsigned short* cand =
      reinterpret_cast<unsigned short*>(smem + 3 * PARTS * CHUNK * 4);
  int* ccnt =
      reinterpret_cast<int*>(smem + 3 * PARTS * CHUNK * 4 + QPB * CSTR * 2);

  const int ql = t >> 3;   // query-local 0..31
  const int part = t & 7;  // 0..7

  if (t < QPB) ccnt[t] = 0;

  // stage points SoA, chunked per part with +4 float pad
  const float* P = xyz + (size_t)b * NN * 3;
  for (int i = t; i < NN; i += 256) {
    const int slot = (i >> 8) * CHUNK + (i & 255);
    px[slot] = P[3 * i + 0];
    py[slot] = P[3 * i + 1];
    pz[slot] = P[3 * i + 2];
  }
  __syncthreads();

  const int q = blockIdx.x * QPB + ql;
  const float* Q = xyz_fp + ((size_t)b * NM + q) * 3;
  const float qx = Q[0], qy = Q[1], qz = Q[2];

  const int pbase = part * CHUNK;

  // ---- pass 1: group mins (8 groups of 32 points per lane) ----
  float gmin[NG];
#pragma unroll
  for (int g = 0; g < NG; g++) {
    float gm = 3.0e38f;
#pragma unroll
    for (int bb = 0; bb < 4; bb++) {
      f2 dd[4];
      dist8p(px, py, pz, pbase + g * 32 + bb * 8, qx, qy, qz, dd);
      gm = fminf(gm, min8p(dd));
    }
    gmin[g] = gm;
  }

  // ---- T = 16th-smallest of the query's 64 group-mins ----
  float s[16];
  {
    float g8[NG];
#pragma unroll
    for (int g = 0; g < NG; g++) g8[g] = gmin[g];
    SORT8(g8)
#pragma unroll
    for (int j = 0; j < 8; j++) s[j] = g8[j];
#pragma unroll
    for (int j = 8; j < 16; j++) s[j] = 3.0e38f;
  }
#pragma unroll
  for (int mask = 1; mask <= 4; mask <<= 1) {
    float B[16];
#pragma unroll
    for (int j = 0; j < 16; j++) B[j] = __shfl_xor(s[j], mask, 64);
    float L[16];
#pragma unroll
    for (int j = 0; j < 16; j++) L[j] = fminf(s[j], B[15 - j]);
    BITONIC16(L)
#pragma unroll
    for (int j = 0; j < 16; j++) s[j] = L[j];
  }
  const float T = s[15];

  // ---- per-lane 8-bit pass mask ----
  unsigned m8 = 0;
#pragma unroll
  for (int g = 0; g < NG; g++) m8 |= (gmin[g] <= T) ? (1u << g) : 0u;

  // ---- butterfly-OR across the query's 8 lanes -> 64-bit group mask ----
  unsigned lo = (part < 4) ? (m8 << (8 * part)) : 0u;
  unsigned hi = (part >= 4) ? (m8 << (8 * (part - 4))) : 0u;
#pragma unroll
  for (int mk = 1; mk <= 4; mk <<= 1) {
    lo |= __shfl_xor(lo, mk, 64);
    hi |= __shfl_xor(hi, mk, 64);
  }
  const unsigned long long vm = ((unsigned long long)hi << 32) | lo;

  // ---- round-robin: k-th set bit -> lane (k & 7) ----
  unsigned long long mym = 0ull;
  {
    unsigned long long m = vm;
    int cnt = 0;
    while (m) {
      const unsigned long long lb = m & (0ull - m);
      if ((cnt & 7) == part) mym |= lb;
      m ^= lb;
      cnt++;
    }
  }

  // ---- pass 2: scan assigned groups; batched slot reservation ----
  while (mym) {
    const int gid = __ffsll(mym) - 1;
    mym &= mym - 1;
    const int gb = (gid >> 3) * CHUNK + (gid & 7) * 32;
    const int ib = (gid >> 3) * PPT + (gid & 7) * 32;
#pragma unroll
    for (int bb = 0; bb < 4; bb++) {
      f2 dd[4];
      dist8p(px, py, pz, gb + bb * 8, qx, qy, qz, dd);
      if (min8p(dd) <= T) {
        unsigned am = 0;
#pragma unroll
        for (int k = 0; k < 4; k++) {
          am |= (dd[k].x <= T) ? (1u << (2 * k)) : 0u;
          am |= (dd[k].y <= T) ? (1u << (2 * k + 1)) : 0u;
        }
        int pos = atomicAdd(&ccnt[ql], __popc(am));
        while (am) {
          const int k = __ffs(am) - 1;
          am &= am - 1;
          if (pos < CAP)
            cand[ql * CSTR + pos] = (unsigned short)(ib + bb * 8 + k);
          pos++;
        }
      }
    }
  }
  __syncthreads();

  // ---- phase 3: exact top-16, 8-lane parallel (local sort + bitonic
  //      shfl merges). Keys unique -> order bit-identical to serial. ----
  {
    const int cnt = ccnt[ql];
    if (cnt <= CAP) {
      unsigned long long kb8[8];
      // gather this lane's strided candidates: part, part+8, ...
#pragma unroll
      for (int i = 0; i < 8; i++) {
        const int c = part + 8 * i;
        unsigned long long kk = ~0ULL;
        if (c < cnt) {
          const int idx = cand[ql * CSTR + c];
          const int slot = (idx >> 8) * CHUNK + (idx & 255);
          const float d2 = d2rn(qx, qy, qz, px[slot], py[slot], pz[slot]);
          kk = ((unsigned long long)__float_as_uint(d2) << 32) | (unsigned)idx;
        }
        kb8[i] = kk;
      }
      SORT8U(kb8)

      // round 1 (XOR 1): pair merge -> sorted-16 per lane pair
      {
        unsigned long long bb[8];
#pragma unroll
        for (int j = 0; j < 8; j++) bb[j] = __shfl_xor(kb8[7 - j], 1, 64);
        if (part & 1) {
#pragma unroll
          for (int j = 0; j < 8; j++)
            kb8[j] = (kb8[j] < bb[j]) ? bb[j] : kb8[j];
        } else {
#pragma unroll
          for (int j = 0; j < 8; j++)
            kb8[j] = (kb8[j] < bb[j]) ? kb8[j] : bb[j];
        }
        BSORT8U(kb8)
      }

      // rounds 2,3 (XOR 3 then XOR 5): merge sorted-16s, keep top-16
#pragma unroll
      for (int r = 0; r < 2; r++) {
        const int xm = r ? 5 : 3;
        unsigned long long bb[8];
#pragma unroll
        for (int j = 0; j < 8; j++) bb[j] = __shfl_xor(kb8[7 - j], xm, 64);
#pragma unroll
        for (int j = 0; j < 8; j++)
          kb8[j] = (kb8[j] < bb[j]) ? kb8[j] : bb[j];
#pragma unroll
        for (int j = 0; j < 8; j++) bb[j] = __shfl_xor(kb8[j], 1, 64);
        if (part & 1) {
#pragma unroll
          for (int j = 0; j < 8; j++)
            kb8[j] = (kb8[j] < bb[j]) ? bb[j] : kb8[j];
        } else {
#pragma unroll
          for (int j = 0; j < 8; j++)
            kb8[j] = (kb8[j] < bb[j]) ? kb8[j] : bb[j];
        }
        BSORT8U(kb8)
      }

      // final sorted-16: even lane holds ranks 0-7, odd lane ranks 8-15
      if (part < 2) {
#pragma unroll
        for (int j = 0; j < 8; j++)
          cand[ql * CSTR + part * 8 + j] = (unsigned short)(unsigned)kb8[j];
      }
    } else if (part == 0) {
      // overflow fallback (astronomically rare): serial exact scan
      unsigned long long kb[NK];
#pragma unroll
      for (int j = 0; j < NK; j++) kb[j] = ~0ULL;
      for (int i = 0; i < NN; i++) {
        const int slot = (i >> 8) * CHUNK + (i & 255);
        const float d2 = d2rn(qx, qy, qz, px[slot], py[slot], pz[slot]);
        unsigned long long kk =
            ((unsigned long long)__float_as_uint(d2) << 32) | (unsigned)i;
        if (kk < kb[NK - 1]) {
#pragma unroll
          for (int j = 0; j < NK; j++) {
            const bool c2 = kk < kb[j];
            const unsigned long long lo2 = c2 ? kk : kb[j];
            const unsigned long long hi2 = c2 ? kb[j] : kk;
            kb[j] = lo2;
            kk = hi2;
          }
        }
      }
#pragma unroll
      for (int j = 0; j < NK; j++)
        cand[ql * CSTR + j] = (unsigned short)(unsigned)kb[j];
    }
  }
  __syncthreads();

  // ---- output: each part lane writes 2 neighbors (6 floats) ----
  float* o = out_knn + ((size_t)(b * NM + q)) * (NK * 3);
#pragma unroll
  for (int jj = 0; jj < 2; jj++) {
    const int j = part * 2 + jj;
    const int i = cand[ql * CSTR + j];
    const int slot = (i >> 8) * CHUNK + (i & 255);
    o[3 * j + 0] = px[slot];
    o[3 * j + 1] = py[slot];
    o[3 * j + 2] = pz[slot];
  }
}

// ---------------------------------------------------------------------------
extern "C" void kernel_launch(void* const* d_in, const int* in_sizes, int n_in,
                              void* d_out, int out_size, void* d_ws,
                              size_t ws_size, hipStream_t stream) {
  const float* xyz      = (const float*)d_in[0];  // [8,2048,3]
  const float* xyz_fp   = (const float*)d_in[1];  // [8,8192,3]
  const float* features = (const float*)d_in[2];  // [8,64,2048]
  const float* W1 = (const float*)d_in[4];        // [64,64]
  const float* b1 = (const float*)d_in[5];        // [64]

  float* out_feats = (float*)d_out;                       // 8*2048*64
  float* out_knn   = out_feats + (size_t)NB * NN * NC;    // 8*8192*16*3
  float* out_x     = out_knn + (size_t)NB * NM * NK * 3;  // 8*2048*64

  fused_kernel<<<dim3(KB + FB, NB), 256, 0, stream>>>(
      features, W1, b1, out_feats, out_x, xyz, xyz_fp, out_knn);
}

// Round 13
// 138.699 us; speedup vs baseline: 1.5346x; 1.0006x over previous
//
#include <hip/hip_runtime.h>

#define NB 8
#define NN 2048
#define NM 8192
#define NC 64
#define ND 64
#define NK 16

#define PARTS 8     // lanes per query
#define PPT 256     // points per lane (NN / PARTS)
#define CHUNK 260   // padded chunk stride in floats: 260%32==4 -> chunks on
                    // distinct bank-quads for pass-1 broadcast reads
#define QPB 32      // queries per block (256 threads / 8 parts)
#define NG 8        // groups of 32 points per lane
#define CAP 64      // candidate slots per query (overflow prob ~e^-40 + exact fallback)
#define CSTR 66     // cand row stride in u16

#define KB (NM / QPB)       // knn blocks per batch (256) -- FIRST in grid
#define FB (NN / 64)        // feats blocks per batch (32) -- after knn
#define SMEM_BYTES 29312    // knn: 3*8*260*4 + 32*66*2 + 32*4 = 29312 (5/CU)
                            // feats: tile only = 64*68*4 = 17408 (W in regs)
// r8/r9: 512-thread blocks regress ~17% even without spills.
// r10: packed dist8p freed VALU (64->56%) but time flat.
// r11: 8-lane-parallel phase 3 was the real long pole: 120 -> 73.5 us.
// r12: batched atomics +5us; CSTR pad did NOT cut conflicts -> they're in
//      pass-2 reads (g*32 mod 32 == 0: group can't touch bank). Fixed here
//      by block swizzle B' = B ^ (B>>2) inside each chunk (bijective).

typedef __attribute__((ext_vector_type(2))) float f2;
typedef __attribute__((ext_vector_type(4))) float f4;

// physical LDS slot of logical point index i (0..2047)
__device__ __forceinline__ int slotOf(int i) {
  const int B = (i & 255) >> 3;        // logical block in chunk
  const int BS = B ^ (B >> 2);         // bank-swizzled block
  return (i >> 8) * CHUNK + (BS << 3) + (i & 7);
}

__device__ __forceinline__ float d2rn(float qx, float qy, float qz, float x,
                                      float y, float z) {
  const float dx = __fsub_rn(qx, x);
  const float dy = __fsub_rn(qy, y);
  const float dz = __fsub_rn(qz, z);
  return __fadd_rn(__fadd_rn(__fmul_rn(dx, dx), __fmul_rn(dy, dy)),
                   __fmul_rn(dz, dz));
}

#define CE(a, i, j)                     \
  {                                     \
    const float lo = fminf(a[i], a[j]); \
    const float hi = fmaxf(a[i], a[j]); \
    a[i] = lo;                          \
    a[j] = hi;                          \
  }

// u64 compare-exchange (ascending)
#define CEU(a, i, j)                                      \
  {                                                       \
    const bool c_ = a[i] < a[j];                          \
    const unsigned long long lo_ = c_ ? a[i] : a[j];      \
    const unsigned long long hi_ = c_ ? a[j] : a[i];      \
    a[i] = lo_;                                           \
    a[j] = hi_;                                           \
  }

// Batcher odd-even sort of d[8] ascending (19 comparators) -- float
#define SORT8(d)                                  \
  CE(d, 0, 1) CE(d, 2, 3) CE(d, 4, 5) CE(d, 6, 7) \
  CE(d, 0, 2) CE(d, 1, 3) CE(d, 4, 6) CE(d, 5, 7) \
  CE(d, 1, 2) CE(d, 5, 6)                         \
  CE(d, 0, 4) CE(d, 1, 5) CE(d, 2, 6) CE(d, 3, 7) \
  CE(d, 2, 4) CE(d, 3, 5)                         \
  CE(d, 1, 2) CE(d, 3, 4) CE(d, 5, 6)

// Batcher odd-even sort of u64[8] ascending (19 comparators)
#define SORT8U(d)                                          \
  CEU(d, 0, 1) CEU(d, 2, 3) CEU(d, 4, 5) CEU(d, 6, 7)      \
  CEU(d, 0, 2) CEU(d, 1, 3) CEU(d, 4, 6) CEU(d, 5, 7)      \
  CEU(d, 1, 2) CEU(d, 5, 6)                                \
  CEU(d, 0, 4) CEU(d, 1, 5) CEU(d, 2, 6) CEU(d, 3, 7)      \
  CEU(d, 2, 4) CEU(d, 3, 5)                                \
  CEU(d, 1, 2) CEU(d, 3, 4) CEU(d, 5, 6)

// bitonic-8 sorter (input must be bitonic) -- u64, 12 comparators
#define BSORT8U(d)                                         \
  CEU(d, 0, 4) CEU(d, 1, 5) CEU(d, 2, 6) CEU(d, 3, 7)      \
  CEU(d, 0, 2) CEU(d, 1, 3) CEU(d, 4, 6) CEU(d, 5, 7)      \
  CEU(d, 0, 1) CEU(d, 2, 3) CEU(d, 4, 5) CEU(d, 6, 7)

// bitonic sort of L[16] (input bitonic) ascending: 32 comparators -- float
#define BITONIC16(L)                                                      \
  CE(L, 0, 8) CE(L, 1, 9) CE(L, 2, 10) CE(L, 3, 11) CE(L, 4, 12)          \
  CE(L, 5, 13) CE(L, 6, 14) CE(L, 7, 15)                                  \
  CE(L, 0, 4) CE(L, 1, 5) CE(L, 2, 6) CE(L, 3, 7) CE(L, 8, 12)            \
  CE(L, 9, 13) CE(L, 10, 14) CE(L, 11, 15)                                \
  CE(L, 0, 2) CE(L, 1, 3) CE(L, 4, 6) CE(L, 5, 7) CE(L, 8, 10)            \
  CE(L, 9, 11) CE(L, 12, 14) CE(L, 13, 15)                                \
  CE(L, 0, 1) CE(L, 2, 3) CE(L, 4, 5) CE(L, 6, 7) CE(L, 8, 9)             \
  CE(L, 10, 11) CE(L, 12, 13) CE(L, 14, 15)

// Packed-pair distance: 8 points -> 4 f2 of d^2 (v_pk_* eligible; bitwise
// identical to scalar _rn per half; contract(off) forbids FMA fusion).
__device__ __forceinline__ void dist8p(const float* px, const float* py,
                                       const float* pz, int base, float qx,
                                       float qy, float qz, f2 dd[4]) {
#pragma clang fp contract(off)
  const f4 X0 = *(const f4*)&px[base];
  const f4 X1 = *(const f4*)&px[base + 4];
  const f4 Y0 = *(const f4*)&py[base];
  const f4 Y1 = *(const f4*)&py[base + 4];
  const f4 Z0 = *(const f4*)&pz[base];
  const f4 Z1 = *(const f4*)&pz[base + 4];
  const f2 qvx = {qx, qx}, qvy = {qy, qy}, qvz = {qz, qz};
  {
    const f2 dx = qvx - X0.xy, dy = qvy - Y0.xy, dz = qvz - Z0.xy;
    dd[0] = (dx * dx + dy * dy) + dz * dz;
  }
  {
    const f2 dx = qvx - X0.zw, dy = qvy - Y0.zw, dz = qvz - Z0.zw;
    dd[1] = (dx * dx + dy * dy) + dz * dz;
  }
  {
    const f2 dx = qvx - X1.xy, dy = qvy - Y1.xy, dz = qvz - Z1.xy;
    dd[2] = (dx * dx + dy * dy) + dz * dz;
  }
  {
    const f2 dx = qvx - X1.zw, dy = qvy - Y1.zw, dz = qvz - Z1.zw;
    dd[3] = (dx * dx + dy * dy) + dz * dz;
  }
}

__device__ __forceinline__ float min8p(const f2 dd[4]) {
  return fminf(fminf(fminf(dd[0].x, dd[0].y), fminf(dd[1].x, dd[1].y)),
               fminf(fminf(dd[2].x, dd[2].y), fminf(dd[3].x, dd[3].y)));
}

// ---------------------------------------------------------------------------
// Fused kernel (r12 structure); delta: chunk-internal block swizzle
// B' = B ^ (B>>2) applied at all 5 LDS access sites -> pass-2 reads spread
// across bank quads (conflict degree ~8 -> ~2).
// ---------------------------------------------------------------------------
__global__ __launch_bounds__(256, 4) void fused_kernel(
    const float* __restrict__ features, const float* __restrict__ W1,
    const float* __restrict__ b1, float* __restrict__ out_feats,
    float* __restrict__ out_x, const float* __restrict__ xyz,
    const float* __restrict__ xyz_fp, float* __restrict__ out_knn) {
  __shared__ __align__(16) unsigned char smem[SMEM_BYTES];

  const int b = blockIdx.y;
  const int t = threadIdx.x;

  if (blockIdx.x >= KB) {
    // ================= feats + linear path (verbatim r7) =================
    float(*tile)[68] = reinterpret_cast<float(*)[68]>(smem);  // 17408 B

    const int n0 = (blockIdx.x - KB) * 64;
    const int lane = t & 63;
    const int grp = t >> 6;

    for (int c = grp; c < NC; c += 4)
      tile[c][lane] = features[((size_t)(b * NC + c) * NN) + n0 + lane];

    float4 wreg[16];
    {
      const float4* Wr = (const float4*)(W1 + lane * NC);
#pragma unroll
      for (int k = 0; k < 16; k++) wreg[k] = Wr[k];
    }
    __syncthreads();

    for (int j = grp; j < 64; j += 4)
      out_feats[((size_t)(b * NN + n0 + j) * NC) + lane] = tile[lane][j];

    const int d = lane;
    float acc[16];
    const float bd = b1[d];
#pragma unroll
    for (int jj = 0; jj < 16; jj++) acc[jj] = bd;

    const float4* tv = (const float4*)&tile[0][0];
#pragma unroll
    for (int k = 0; k < 16; k++) {
#pragma unroll
      for (int cc = 0; cc < 4; cc++) {
        const int c = k * 4 + cc;
        const float w = (cc == 0)   ? wreg[k].x
                        : (cc == 1) ? wreg[k].y
                        : (cc == 2) ? wreg[k].z
                                    : wreg[k].w;
#pragma unroll
        for (int q = 0; q < 4; q++) {
          const float4 v = tv[c * 17 + grp * 4 + q];
          acc[q * 4 + 0] = fmaf(v.x, w, acc[q * 4 + 0]);
          acc[q * 4 + 1] = fmaf(v.y, w, acc[q * 4 + 1]);
          acc[q * 4 + 2] = fmaf(v.z, w, acc[q * 4 + 2]);
          acc[q * 4 + 3] = fmaf(v.w, w, acc[q * 4 + 3]);
        }
      }
    }
#pragma unroll
    for (int jj = 0; jj < 16; jj++) {
      const int j = grp * 16 + jj;
      out_x[((size_t)(b * NN + n0 + j) * ND) + d] = acc[jj];
    }
    return;
  }

  // ======================= kNN path =======================
  float* px = reinterpret_cast<float*>(smem);
  float* py = px + PARTS * CHUNK;
  float* pz = py + PARTS * CHUNK;
  unsigned short* cand =
      reinterpret_cast<unsigned short*>(smem + 3 * PARTS * CHUNK * 4);
  int* ccnt =
      reinterpret_cast<int*>(smem + 3 * PARTS * CHUNK * 4 + QPB * CSTR * 2);

  const int ql = t >> 3;   // query-local 0..31
  const int part = t & 7;  // 0..7

  if (t < QPB) ccnt[t] = 0;

  // stage points SoA into swizzled slots
  const float* P = xyz + (size_t)b * NN * 3;
  for (int i = t; i < NN; i += 256) {
    const int slot = slotOf(i);
    px[slot] = P[3 * i + 0];
    py[slot] = P[3 * i + 1];
    pz[slot] = P[3 * i + 2];
  }
  __syncthreads();

  const int q = blockIdx.x * QPB + ql;
  const float* Q = xyz_fp + ((size_t)b * NM + q) * 3;
  const float qx = Q[0], qy = Q[1], qz = Q[2];

  const int pbase = part * CHUNK;

  // ---- pass 1: group mins (swizzled base is compile-time per (g,bb)) ----
  float gmin[NG];
#pragma unroll
  for (int g = 0; g < NG; g++) {
    float gm = 3.0e38f;
#pragma unroll
    for (int bb = 0; bb < 4; bb++) {
      const int B = g * 4 + bb;
      const int BS = B ^ (B >> 2);
      f2 dd[4];
      dist8p(px, py, pz, pbase + BS * 8, qx, qy, qz, dd);
      gm = fminf(gm, min8p(dd));
    }
    gmin[g] = gm;
  }

  // ---- T = 16th-smallest of the query's 64 group-mins ----
  float s[16];
  {
    float g8[NG];
#pragma unroll
    for (int g = 0; g < NG; g++) g8[g] = gmin[g];
    SORT8(g8)
#pragma unroll
    for (int j = 0; j < 8; j++) s[j] = g8[j];
#pragma unroll
    for (int j = 8; j < 16; j++) s[j] = 3.0e38f;
  }
#pragma unroll
  for (int mask = 1; mask <= 4; mask <<= 1) {
    float B[16];
#pragma unroll
    for (int j = 0; j < 16; j++) B[j] = __shfl_xor(s[j], mask, 64);
    float L[16];
#pragma unroll
    for (int j = 0; j < 16; j++) L[j] = fminf(s[j], B[15 - j]);
    BITONIC16(L)
#pragma unroll
    for (int j = 0; j < 16; j++) s[j] = L[j];
  }
  const float T = s[15];

  // ---- per-lane 8-bit pass mask ----
  unsigned m8 = 0;
#pragma unroll
  for (int g = 0; g < NG; g++) m8 |= (gmin[g] <= T) ? (1u << g) : 0u;

  // ---- butterfly-OR across the query's 8 lanes -> 64-bit group mask ----
  unsigned lo = (part < 4) ? (m8 << (8 * part)) : 0u;
  unsigned hi = (part >= 4) ? (m8 << (8 * (part - 4))) : 0u;
#pragma unroll
  for (int mk = 1; mk <= 4; mk <<= 1) {
    lo |= __shfl_xor(lo, mk, 64);
    hi |= __shfl_xor(hi, mk, 64);
  }
  const unsigned long long vm = ((unsigned long long)hi << 32) | lo;

  // ---- round-robin: k-th set bit -> lane (k & 7) ----
  unsigned long long mym = 0ull;
  {
    unsigned long long m = vm;
    int cnt = 0;
    while (m) {
      const unsigned long long lb = m & (0ull - m);
      if ((cnt & 7) == part) mym |= lb;
      m ^= lb;
      cnt++;
    }
  }

  // ---- pass 2: scan assigned groups; batched slot reservation ----
  while (mym) {
    const int gid = __ffsll(mym) - 1;
    mym &= mym - 1;
    const int cb = (gid >> 3) * CHUNK;
    const int goff = gid & 7;
    const int ib = (gid >> 3) * PPT + goff * 32;
#pragma unroll
    for (int bb = 0; bb < 4; bb++) {
      const int B = goff * 4 + bb;
      const int BS = B ^ (B >> 2);
      f2 dd[4];
      dist8p(px, py, pz, cb + BS * 8, qx, qy, qz, dd);
      if (min8p(dd) <= T) {
        unsigned am = 0;
#pragma unroll
        for (int k = 0; k < 4; k++) {
          am |= (dd[k].x <= T) ? (1u << (2 * k)) : 0u;
          am |= (dd[k].y <= T) ? (1u << (2 * k + 1)) : 0u;
        }
        int pos = atomicAdd(&ccnt[ql], __popc(am));
        while (am) {
          const int k = __ffs(am) - 1;
          am &= am - 1;
          if (pos < CAP)
            cand[ql * CSTR + pos] = (unsigned short)(ib + bb * 8 + k);
          pos++;
        }
      }
    }
  }
  __syncthreads();

  // ---- phase 3: exact top-16, 8-lane parallel (local sort + bitonic
  //      shfl merges). Keys unique -> order bit-identical to serial. ----
  {
    const int cnt = ccnt[ql];
    if (cnt <= CAP) {
      unsigned long long kb8[8];
      // gather this lane's strided candidates: part, part+8, ...
#pragma unroll
      for (int i = 0; i < 8; i++) {
        const int c = part + 8 * i;
        unsigned long long kk = ~0ULL;
        if (c < cnt) {
          const int idx = cand[ql * CSTR + c];
          const int slot = slotOf(idx);
          const float d2 = d2rn(qx, qy, qz, px[slot], py[slot], pz[slot]);
          kk = ((unsigned long long)__float_as_uint(d2) << 32) | (unsigned)idx;
        }
        kb8[i] = kk;
      }
      SORT8U(kb8)

      // round 1 (XOR 1): pair merge -> sorted-16 per lane pair
      {
        unsigned long long bb[8];
#pragma unroll
        for (int j = 0; j < 8; j++) bb[j] = __shfl_xor(kb8[7 - j], 1, 64);
        if (part & 1) {
#pragma unroll
          for (int j = 0; j < 8; j++)
            kb8[j] = (kb8[j] < bb[j]) ? bb[j] : kb8[j];
        } else {
#pragma unroll
          for (int j = 0; j < 8; j++)
            kb8[j] = (kb8[j] < bb[j]) ? kb8[j] : bb[j];
        }
        BSORT8U(kb8)
      }

      // rounds 2,3 (XOR 3 then XOR 5): merge sorted-16s, keep top-16
#pragma unroll
      for (int r = 0; r < 2; r++) {
        const int xm = r ? 5 : 3;
        unsigned long long bb[8];
#pragma unroll
        for (int j = 0; j < 8; j++) bb[j] = __shfl_xor(kb8[7 - j], xm, 64);
#pragma unroll
        for (int j = 0; j < 8; j++)
          kb8[j] = (kb8[j] < bb[j]) ? kb8[j] : bb[j];
#pragma unroll
        for (int j = 0; j < 8; j++) bb[j] = __shfl_xor(kb8[j], 1, 64);
        if (part & 1) {
#pragma unroll
          for (int j = 0; j < 8; j++)
            kb8[j] = (kb8[j] < bb[j]) ? bb[j] : kb8[j];
        } else {
#pragma unroll
          for (int j = 0; j < 8; j++)
            kb8[j] = (kb8[j] < bb[j]) ? kb8[j] : bb[j];
        }
        BSORT8U(kb8)
      }

      // final sorted-16: even lane holds ranks 0-7, odd lane ranks 8-15
      if (part < 2) {
#pragma unroll
        for (int j = 0; j < 8; j++)
          cand[ql * CSTR + part * 8 + j] = (unsigned short)(unsigned)kb8[j];
      }
    } else if (part == 0) {
      // overflow fallback (astronomically rare): serial exact scan
      unsigned long long kb[NK];
#pragma unroll
      for (int j = 0; j < NK; j++) kb[j] = ~0ULL;
      for (int i = 0; i < NN; i++) {
        const int slot = slotOf(i);
        const float d2 = d2rn(qx, qy, qz, px[slot], py[slot], pz[slot]);
        unsigned long long kk =
            ((unsigned long long)__float_as_uint(d2) << 32) | (unsigned)i;
        if (kk < kb[NK - 1]) {
#pragma unroll
          for (int j = 0; j < NK; j++) {
            const bool c2 = kk < kb[j];
            const unsigned long long lo2 = c2 ? kk : kb[j];
            const unsigned long long hi2 = c2 ? kb[j] : kk;
            kb[j] = lo2;
            kk = hi2;
          }
        }
      }
#pragma unroll
      for (int j = 0; j < NK; j++)
        cand[ql * CSTR + j] = (unsigned short)(unsigned)kb[j];
    }
  }
  __syncthreads();

  // ---- output: each part lane writes 2 neighbors (6 floats) ----
  float* o = out_knn + ((size_t)(b * NM + q)) * (NK * 3);
#pragma unroll
  for (int jj = 0; jj < 2; jj++) {
    const int j = part * 2 + jj;
    const int i = cand[ql * CSTR + j];
    const int slot = slotOf(i);
    o[3 * j + 0] = px[slot];
    o[3 * j + 1] = py[slot];
    o[3 * j + 2] = pz[slot];
  }
}

// ---------------------------------------------------------------------------
extern "C" void kernel_launch(void* const* d_in, const int* in_sizes, int n_in,
                              void* d_out, int out_size, void* d_ws,
                              size_t ws_size, hipStream_t stream) {
  const float* xyz      = (const float*)d_in[0];  // [8,2048,3]
  const float* xyz_fp   = (const float*)d_in[1];  // [8,8192,3]
  const float* features = (const float*)d_in[2];  // [8,64,2048]
  const float* W1 = (const float*)d_in[4];        // [64,64]
  const float* b1 = (const float*)d_in[5];        // [64]

  float* out_feats = (float*)d_out;                       // 8*2048*64
  float* out_knn   = out_feats + (size_t)NB * NN * NC;    // 8*8192*16*3
  float* out_x     = out_knn + (size_t)NB * NM * NK * 3;  // 8*2048*64

  fused_kernel<<<dim3(KB + FB, NB), 256, 0, stream>>>(
      features, W1, b1, out_feats, out_x, xyz, xyz_fp, out_knn);
}

// Round 14
// 136.999 us; speedup vs baseline: 1.5536x; 1.0124x over previous
//
#include <hip/hip_runtime.h>

#define NB 8
#define NN 2048
#define NM 8192
#define NC 64
#define ND 64
#define NK 16

#define PARTS 8     // lanes per query
#define PPT 256     // points per lane (NN / PARTS)
#define CHUNK 260   // padded chunk stride in floats: 260%32==4 -> chunks on
                    // distinct bank-quads for pass-1 broadcast reads
#define QPB 32      // queries per block (256 threads / 8 parts)
#define NG 8        // groups of 32 points per lane
#define CAP 64      // candidate slots per query (overflow prob ~e^-40 + exact fallback)
#define CSTR 66     // cand row stride in u16

#define KB (NM / QPB)       // knn blocks per batch (256) -- FIRST in grid
#define FB (NN / 64)        // feats blocks per batch (32) -- after knn
#define SMEM_BYTES 29312    // knn: 3*8*260*4 + 32*66*2 + 32*4 = 29312 (5/CU)
                            // feats: tile only = 64*68*4 = 17408 (W in regs)
// r8/r9: 512-thread blocks regress ~17% even without spills.
// r10: packed dist8p freed VALU (64->56%) but time flat.
// r11: 8-lane-parallel phase 3 was the real long pole: 120 -> 73.5 us.
// r12: batched atomics +5us; CSTR pad didn't cut conflicts.
// r13: block swizzle cut conflicts 4.49M->3.06M, time flat (latency-hidden).
// r14: a query's 8 lanes are contiguous -> SAME WAVE. cand/ccnt traffic is
//      intra-wave (in-order visible). Only the staging barrier is needed;
//      the post-pass-2 and post-phase-3 barriers are deleted (skew tails).

typedef __attribute__((ext_vector_type(2))) float f2;
typedef __attribute__((ext_vector_type(4))) float f4;

// physical LDS slot of logical point index i (0..2047)
__device__ __forceinline__ int slotOf(int i) {
  const int B = (i & 255) >> 3;        // logical block in chunk
  const int BS = B ^ (B >> 2);         // bank-swizzled block
  return (i >> 8) * CHUNK + (BS << 3) + (i & 7);
}

__device__ __forceinline__ float d2rn(float qx, float qy, float qz, float x,
                                      float y, float z) {
  const float dx = __fsub_rn(qx, x);
  const float dy = __fsub_rn(qy, y);
  const float dz = __fsub_rn(qz, z);
  return __fadd_rn(__fadd_rn(__fmul_rn(dx, dx), __fmul_rn(dy, dy)),
                   __fmul_rn(dz, dz));
}

#define CE(a, i, j)                     \
  {                                     \
    const float lo = fminf(a[i], a[j]); \
    const float hi = fmaxf(a[i], a[j]); \
    a[i] = lo;                          \
    a[j] = hi;                          \
  }

// u64 compare-exchange (ascending)
#define CEU(a, i, j)                                      \
  {                                                       \
    const bool c_ = a[i] < a[j];                          \
    const unsigned long long lo_ = c_ ? a[i] : a[j];      \
    const unsigned long long hi_ = c_ ? a[j] : a[i];      \
    a[i] = lo_;                                           \
    a[j] = hi_;                                           \
  }

// Batcher odd-even sort of d[8] ascending (19 comparators) -- float
#define SORT8(d)                                  \
  CE(d, 0, 1) CE(d, 2, 3) CE(d, 4, 5) CE(d, 6, 7) \
  CE(d, 0, 2) CE(d, 1, 3) CE(d, 4, 6) CE(d, 5, 7) \
  CE(d, 1, 2) CE(d, 5, 6)                         \
  CE(d, 0, 4) CE(d, 1, 5) CE(d, 2, 6) CE(d, 3, 7) \
  CE(d, 2, 4) CE(d, 3, 5)                         \
  CE(d, 1, 2) CE(d, 3, 4) CE(d, 5, 6)

// Batcher odd-even sort of u64[8] ascending (19 comparators)
#define SORT8U(d)                                          \
  CEU(d, 0, 1) CEU(d, 2, 3) CEU(d, 4, 5) CEU(d, 6, 7)      \
  CEU(d, 0, 2) CEU(d, 1, 3) CEU(d, 4, 6) CEU(d, 5, 7)      \
  CEU(d, 1, 2) CEU(d, 5, 6)                                \
  CEU(d, 0, 4) CEU(d, 1, 5) CEU(d, 2, 6) CEU(d, 3, 7)      \
  CEU(d, 2, 4) CEU(d, 3, 5)                                \
  CEU(d, 1, 2) CEU(d, 3, 4) CEU(d, 5, 6)

// bitonic-8 sorter (input must be bitonic) -- u64, 12 comparators
#define BSORT8U(d)                                         \
  CEU(d, 0, 4) CEU(d, 1, 5) CEU(d, 2, 6) CEU(d, 3, 7)      \
  CEU(d, 0, 2) CEU(d, 1, 3) CEU(d, 4, 6) CEU(d, 5, 7)      \
  CEU(d, 0, 1) CEU(d, 2, 3) CEU(d, 4, 5) CEU(d, 6, 7)

// bitonic sort of L[16] (input bitonic) ascending: 32 comparators -- float
#define BITONIC16(L)                                                      \
  CE(L, 0, 8) CE(L, 1, 9) CE(L, 2, 10) CE(L, 3, 11) CE(L, 4, 12)          \
  CE(L, 5, 13) CE(L, 6, 14) CE(L, 7, 15)                                  \
  CE(L, 0, 4) CE(L, 1, 5) CE(L, 2, 6) CE(L, 3, 7) CE(L, 8, 12)            \
  CE(L, 9, 13) CE(L, 10, 14) CE(L, 11, 15)                                \
  CE(L, 0, 2) CE(L, 1, 3) CE(L, 4, 6) CE(L, 5, 7) CE(L, 8, 10)            \
  CE(L, 9, 11) CE(L, 12, 14) CE(L, 13, 15)                                \
  CE(L, 0, 1) CE(L, 2, 3) CE(L, 4, 5) CE(L, 6, 7) CE(L, 8, 9)             \
  CE(L, 10, 11) CE(L, 12, 13) CE(L, 14, 15)

// Packed-pair distance: 8 points -> 4 f2 of d^2 (v_pk_* eligible; bitwise
// identical to scalar _rn per half; contract(off) forbids FMA fusion).
__device__ __forceinline__ void dist8p(const float* px, const float* py,
                                       const float* pz, int base, float qx,
                                       float qy, float qz, f2 dd[4]) {
#pragma clang fp contract(off)
  const f4 X0 = *(const f4*)&px[base];
  const f4 X1 = *(const f4*)&px[base + 4];
  const f4 Y0 = *(const f4*)&py[base];
  const f4 Y1 = *(const f4*)&py[base + 4];
  const f4 Z0 = *(const f4*)&pz[base];
  const f4 Z1 = *(const f4*)&pz[base + 4];
  const f2 qvx = {qx, qx}, qvy = {qy, qy}, qvz = {qz, qz};
  {
    const f2 dx = qvx - X0.xy, dy = qvy - Y0.xy, dz = qvz - Z0.xy;
    dd[0] = (dx * dx + dy * dy) + dz * dz;
  }
  {
    const f2 dx = qvx - X0.zw, dy = qvy - Y0.zw, dz = qvz - Z0.zw;
    dd[1] = (dx * dx + dy * dy) + dz * dz;
  }
  {
    const f2 dx = qvx - X1.xy, dy = qvy - Y1.xy, dz = qvz - Z1.xy;
    dd[2] = (dx * dx + dy * dy) + dz * dz;
  }
  {
    const f2 dx = qvx - X1.zw, dy = qvy - Y1.zw, dz = qvz - Z1.zw;
    dd[3] = (dx * dx + dy * dy) + dz * dz;
  }
}

__device__ __forceinline__ float min8p(const f2 dd[4]) {
  return fminf(fminf(fminf(dd[0].x, dd[0].y), fminf(dd[1].x, dd[1].y)),
               fminf(fminf(dd[2].x, dd[2].y), fminf(dd[3].x, dd[3].y)));
}

// ---------------------------------------------------------------------------
// Fused kernel (r13 structure); delta: only ONE __syncthreads (staging).
// All cand/ccnt traffic for a query stays within its own wave.
// ---------------------------------------------------------------------------
__global__ __launch_bounds__(256, 4) void fused_kernel(
    const float* __restrict__ features, const float* __restrict__ W1,
    const float* __restrict__ b1, float* __restrict__ out_feats,
    float* __restrict__ out_x, const float* __restrict__ xyz,
    const float* __restrict__ xyz_fp, float* __restrict__ out_knn) {
  __shared__ __align__(16) unsigned char smem[SMEM_BYTES];

  const int b = blockIdx.y;
  const int t = threadIdx.x;

  if (blockIdx.x >= KB) {
    // ================= feats + linear path (verbatim r7) =================
    float(*tile)[68] = reinterpret_cast<float(*)[68]>(smem);  // 17408 B

    const int n0 = (blockIdx.x - KB) * 64;
    const int lane = t & 63;
    const int grp = t >> 6;

    for (int c = grp; c < NC; c += 4)
      tile[c][lane] = features[((size_t)(b * NC + c) * NN) + n0 + lane];

    float4 wreg[16];
    {
      const float4* Wr = (const float4*)(W1 + lane * NC);
#pragma unroll
      for (int k = 0; k < 16; k++) wreg[k] = Wr[k];
    }
    __syncthreads();

    for (int j = grp; j < 64; j += 4)
      out_feats[((size_t)(b * NN + n0 + j) * NC) + lane] = tile[lane][j];

    const int d = lane;
    float acc[16];
    const float bd = b1[d];
#pragma unroll
    for (int jj = 0; jj < 16; jj++) acc[jj] = bd;

    const float4* tv = (const float4*)&tile[0][0];
#pragma unroll
    for (int k = 0; k < 16; k++) {
#pragma unroll
      for (int cc = 0; cc < 4; cc++) {
        const int c = k * 4 + cc;
        const float w = (cc == 0)   ? wreg[k].x
                        : (cc == 1) ? wreg[k].y
                        : (cc == 2) ? wreg[k].z
                                    : wreg[k].w;
#pragma unroll
        for (int q = 0; q < 4; q++) {
          const float4 v = tv[c * 17 + grp * 4 + q];
          acc[q * 4 + 0] = fmaf(v.x, w, acc[q * 4 + 0]);
          acc[q * 4 + 1] = fmaf(v.y, w, acc[q * 4 + 1]);
          acc[q * 4 + 2] = fmaf(v.z, w, acc[q * 4 + 2]);
          acc[q * 4 + 3] = fmaf(v.w, w, acc[q * 4 + 3]);
        }
      }
    }
#pragma unroll
    for (int jj = 0; jj < 16; jj++) {
      const int j = grp * 16 + jj;
      out_x[((size_t)(b * NN + n0 + j) * ND) + d] = acc[jj];
    }
    return;
  }

  // ======================= kNN path =======================
  float* px = reinterpret_cast<float*>(smem);
  float* py = px + PARTS * CHUNK;
  float* pz = py + PARTS * CHUNK;
  unsigned short* cand =
      reinterpret_cast<unsigned short*>(smem + 3 * PARTS * CHUNK * 4);
  int* ccnt =
      reinterpret_cast<int*>(smem + 3 * PARTS * CHUNK * 4 + QPB * CSTR * 2);

  const int ql = t >> 3;   // query-local 0..31 (lanes ql*8..ql*8+7: one wave)
  const int part = t & 7;  // 0..7

  if (t < QPB) ccnt[t] = 0;

  // stage points SoA into swizzled slots
  const float* P = xyz + (size_t)b * NN * 3;
  for (int i = t; i < NN; i += 256) {
    const int slot = slotOf(i);
    px[slot] = P[3 * i + 0];
    py[slot] = P[3 * i + 1];
    pz[slot] = P[3 * i + 2];
  }
  __syncthreads();  // the ONLY block barrier: staging + ccnt init visibility

  const int q = blockIdx.x * QPB + ql;
  const float* Q = xyz_fp + ((size_t)b * NM + q) * 3;
  const float qx = Q[0], qy = Q[1], qz = Q[2];

  const int pbase = part * CHUNK;

  // ---- pass 1: group mins (swizzled base is compile-time per (g,bb)) ----
  float gmin[NG];
#pragma unroll
  for (int g = 0; g < NG; g++) {
    float gm = 3.0e38f;
#pragma unroll
    for (int bb = 0; bb < 4; bb++) {
      const int B = g * 4 + bb;
      const int BS = B ^ (B >> 2);
      f2 dd[4];
      dist8p(px, py, pz, pbase + BS * 8, qx, qy, qz, dd);
      gm = fminf(gm, min8p(dd));
    }
    gmin[g] = gm;
  }

  // ---- T = 16th-smallest of the query's 64 group-mins ----
  float s[16];
  {
    float g8[NG];
#pragma unroll
    for (int g = 0; g < NG; g++) g8[g] = gmin[g];
    SORT8(g8)
#pragma unroll
    for (int j = 0; j < 8; j++) s[j] = g8[j];
#pragma unroll
    for (int j = 8; j < 16; j++) s[j] = 3.0e38f;
  }
#pragma unroll
  for (int mask = 1; mask <= 4; mask <<= 1) {
    float B[16];
#pragma unroll
    for (int j = 0; j < 16; j++) B[j] = __shfl_xor(s[j], mask, 64);
    float L[16];
#pragma unroll
    for (int j = 0; j < 16; j++) L[j] = fminf(s[j], B[15 - j]);
    BITONIC16(L)
#pragma unroll
    for (int j = 0; j < 16; j++) s[j] = L[j];
  }
  const float T = s[15];

  // ---- per-lane 8-bit pass mask ----
  unsigned m8 = 0;
#pragma unroll
  for (int g = 0; g < NG; g++) m8 |= (gmin[g] <= T) ? (1u << g) : 0u;

  // ---- butterfly-OR across the query's 8 lanes -> 64-bit group mask ----
  unsigned lo = (part < 4) ? (m8 << (8 * part)) : 0u;
  unsigned hi = (part >= 4) ? (m8 << (8 * (part - 4))) : 0u;
#pragma unroll
  for (int mk = 1; mk <= 4; mk <<= 1) {
    lo |= __shfl_xor(lo, mk, 64);
    hi |= __shfl_xor(hi, mk, 64);
  }
  const unsigned long long vm = ((unsigned long long)hi << 32) | lo;

  // ---- round-robin: k-th set bit -> lane (k & 7) ----
  unsigned long long mym = 0ull;
  {
    unsigned long long m = vm;
    int cnt = 0;
    while (m) {
      const unsigned long long lb = m & (0ull - m);
      if ((cnt & 7) == part) mym |= lb;
      m ^= lb;
      cnt++;
    }
  }

  // ---- pass 2: scan assigned groups; batched slot reservation.
  //      All writes/atomics hit only this query's row -> intra-wave. ----
  while (mym) {
    const int gid = __ffsll(mym) - 1;
    mym &= mym - 1;
    const int cb = (gid >> 3) * CHUNK;
    const int goff = gid & 7;
    const int ib = (gid >> 3) * PPT + goff * 32;
#pragma unroll
    for (int bb = 0; bb < 4; bb++) {
      const int B = goff * 4 + bb;
      const int BS = B ^ (B >> 2);
      f2 dd[4];
      dist8p(px, py, pz, cb + BS * 8, qx, qy, qz, dd);
      if (min8p(dd) <= T) {
        unsigned am = 0;
#pragma unroll
        for (int k = 0; k < 4; k++) {
          am |= (dd[k].x <= T) ? (1u << (2 * k)) : 0u;
          am |= (dd[k].y <= T) ? (1u << (2 * k + 1)) : 0u;
        }
        int pos = atomicAdd(&ccnt[ql], __popc(am));
        while (am) {
          const int k = __ffs(am) - 1;
          am &= am - 1;
          if (pos < CAP)
            cand[ql * CSTR + pos] = (unsigned short)(ib + bb * 8 + k);
          pos++;
        }
      }
    }
  }
  // NO barrier: phase 3 reads only this wave's writes (in-order per wave)

  // ---- phase 3: exact top-16, 8-lane parallel (local sort + bitonic
  //      shfl merges). Keys unique -> order bit-identical to serial. ----
  {
    const int cnt = ccnt[ql];
    if (cnt <= CAP) {
      unsigned long long kb8[8];
      // gather this lane's strided candidates: part, part+8, ...
#pragma unroll
      for (int i = 0; i < 8; i++) {
        const int c = part + 8 * i;
        unsigned long long kk = ~0ULL;
        if (c < cnt) {
          const int idx = cand[ql * CSTR + c];
          const int slot = slotOf(idx);
          const float d2 = d2rn(qx, qy, qz, px[slot], py[slot], pz[slot]);
          kk = ((unsigned long long)__float_as_uint(d2) << 32) | (unsigned)idx;
        }
        kb8[i] = kk;
      }
      SORT8U(kb8)

      // round 1 (XOR 1): pair merge -> sorted-16 per lane pair
      {
        unsigned long long bb[8];
#pragma unroll
        for (int j = 0; j < 8; j++) bb[j] = __shfl_xor(kb8[7 - j], 1, 64);
        if (part & 1) {
#pragma unroll
          for (int j = 0; j < 8; j++)
            kb8[j] = (kb8[j] < bb[j]) ? bb[j] : kb8[j];
        } else {
#pragma unroll
          for (int j = 0; j < 8; j++)
            kb8[j] = (kb8[j] < bb[j]) ? kb8[j] : bb[j];
        }
        BSORT8U(kb8)
      }

      // rounds 2,3 (XOR 3 then XOR 5): merge sorted-16s, keep top-16
#pragma unroll
      for (int r = 0; r < 2; r++) {
        const int xm = r ? 5 : 3;
        unsigned long long bb[8];
#pragma unroll
        for (int j = 0; j < 8; j++) bb[j] = __shfl_xor(kb8[7 - j], xm, 64);
#pragma unroll
        for (int j = 0; j < 8; j++)
          kb8[j] = (kb8[j] < bb[j]) ? kb8[j] : bb[j];
#pragma unroll
        for (int j = 0; j < 8; j++) bb[j] = __shfl_xor(kb8[j], 1, 64);
        if (part & 1) {
#pragma unroll
          for (int j = 0; j < 8; j++)
            kb8[j] = (kb8[j] < bb[j]) ? bb[j] : kb8[j];
        } else {
#pragma unroll
          for (int j = 0; j < 8; j++)
            kb8[j] = (kb8[j] < bb[j]) ? kb8[j] : bb[j];
        }
        BSORT8U(kb8)
      }

      // final sorted-16: even lane holds ranks 0-7, odd lane ranks 8-15
      if (part < 2) {
#pragma unroll
        for (int j = 0; j < 8; j++)
          cand[ql * CSTR + part * 8 + j] = (unsigned short)(unsigned)kb8[j];
      }
    } else if (part == 0) {
      // overflow fallback (astronomically rare): serial exact scan
      unsigned long long kb[NK];
#pragma unroll
      for (int j = 0; j < NK; j++) kb[j] = ~0ULL;
      for (int i = 0; i < NN; i++) {
        const int slot = slotOf(i);
        const float d2 = d2rn(qx, qy, qz, px[slot], py[slot], pz[slot]);
        unsigned long long kk =
            ((unsigned long long)__float_as_uint(d2) << 32) | (unsigned)i;
        if (kk < kb[NK - 1]) {
#pragma unroll
          for (int j = 0; j < NK; j++) {
            const bool c2 = kk < kb[j];
            const unsigned long long lo2 = c2 ? kk : kb[j];
            const unsigned long long hi2 = c2 ? kb[j] : kk;
            kb[j] = lo2;
            kk = hi2;
          }
        }
      }
#pragma unroll
      for (int j = 0; j < NK; j++)
        cand[ql * CSTR + j] = (unsigned short)(unsigned)kb[j];
    }
  }
  // NO barrier: output reads only this wave's phase-3 writes

  // ---- output: each part lane writes 2 neighbors (6 floats) ----
  float* o = out_knn + ((size_t)(b * NM + q)) * (NK * 3);
#pragma unroll
  for (int jj = 0; jj < 2; jj++) {
    const int j = part * 2 + jj;
    const int i = cand[ql * CSTR + j];
    const int slot = slotOf(i);
    o[3 * j + 0] = px[slot];
    o[3 * j + 1] = py[slot];
    o[3 * j + 2] = pz[slot];
  }
}

// ---------------------------------------------------------------------------
extern "C" void kernel_launch(void* const* d_in, const int* in_sizes, int n_in,
                              void* d_out, int out_size, void* d_ws,
                              size_t ws_size, hipStream_t stream) {
  const float* xyz      = (const float*)d_in[0];  // [8,2048,3]
  const float* xyz_fp   = (const float*)d_in[1];  // [8,8192,3]
  const float* features = (const float*)d_in[2];  // [8,64,2048]
  const float* W1 = (const float*)d_in[4];        // [64,64]
  const float* b1 = (const float*)d_in[5];        // [64]

  float* out_feats = (float*)d_out;                       // 8*2048*64
  float* out_knn   = out_feats + (size_t)NB * NN * NC;    // 8*8192*16*3
  float* out_x     = out_knn + (size_t)NB * NM * NK * 3;  // 8*2048*64

  fused_kernel<<<dim3(KB + FB, NB), 256, 0, stream>>>(
      features, W1, b1, out_feats, out_x, xyz, xyz_fp, out_knn);
}

// Round 15
// 130.860 us; speedup vs baseline: 1.6265x; 1.0469x over previous
//
#include <hip/hip_runtime.h>

#define NB 8
#define NN 2048
#define NM 8192
#define NC 64
#define ND 64
#define NK 16

#define PARTS 8     // lanes per query
#define PPT 256     // points per lane (NN / PARTS)
#define CHUNK 260   // padded chunk stride in floats
#define QPB 32      // queries per block (256 threads / 8 parts)
#define NG 8        // groups of 32 points per lane
#define CAP 64      // candidate slots per query
#define CSTR 66     // cand row stride in u16

#define KB (NM / QPB)       // knn blocks per batch (256) -- FIRST in grid
#define FB (NN / 64)        // feats blocks per batch (32) -- after knn
#define SMEM_BYTES 29312    // knn: 3*8*260*4 + 32*66*2 + 32*4 = 29312 (5/CU)
// r8/r9: 512-thread blocks regress ~17% even without spills.
// r10: packed dist8p freed VALU (64->56%) but time flat.
// r11: 8-lane-parallel phase 3: 120 -> 73.5 us.
// r12: batched atomics +5us. r13: swizzle cut conflicts 32%, time flat.
// r14: single-barrier (query's 8 lanes = one wave): 69.8 -> 66.8 us.
// r15: pass-1/2 distances via v_pk_fma (6 ops/pair vs 8); threshold
//      inflated by (1+4e-6) to absorb FMA-vs-exact rounding skew -- the
//      candidate-superset property is preserved, phase-3 d2rn stays exact.

typedef __attribute__((ext_vector_type(2))) float f2;
typedef __attribute__((ext_vector_type(4))) float f4;

// physical LDS slot of logical point index i (0..2047)
__device__ __forceinline__ int slotOf(int i) {
  const int B = (i & 255) >> 3;        // logical block in chunk
  const int BS = B ^ (B >> 2);         // bank-swizzled block
  return (i >> 8) * CHUNK + (BS << 3) + (i & 7);
}

__device__ __forceinline__ float d2rn(float qx, float qy, float qz, float x,
                                      float y, float z) {
  const float dx = __fsub_rn(qx, x);
  const float dy = __fsub_rn(qy, y);
  const float dz = __fsub_rn(qz, z);
  return __fadd_rn(__fadd_rn(__fmul_rn(dx, dx), __fmul_rn(dy, dy)),
                   __fmul_rn(dz, dz));
}

#define CE(a, i, j)                     \
  {                                     \
    const float lo = fminf(a[i], a[j]); \
    const float hi = fmaxf(a[i], a[j]); \
    a[i] = lo;                          \
    a[j] = hi;                          \
  }

// u64 compare-exchange (ascending)
#define CEU(a, i, j)                                      \
  {                                                       \
    const bool c_ = a[i] < a[j];                          \
    const unsigned long long lo_ = c_ ? a[i] : a[j];      \
    const unsigned long long hi_ = c_ ? a[j] : a[i];      \
    a[i] = lo_;                                           \
    a[j] = hi_;                                           \
  }

// Batcher odd-even sort of d[8] ascending (19 comparators) -- float
#define SORT8(d)                                  \
  CE(d, 0, 1) CE(d, 2, 3) CE(d, 4, 5) CE(d, 6, 7) \
  CE(d, 0, 2) CE(d, 1, 3) CE(d, 4, 6) CE(d, 5, 7) \
  CE(d, 1, 2) CE(d, 5, 6)                         \
  CE(d, 0, 4) CE(d, 1, 5) CE(d, 2, 6) CE(d, 3, 7) \
  CE(d, 2, 4) CE(d, 3, 5)                         \
  CE(d, 1, 2) CE(d, 3, 4) CE(d, 5, 6)

// Batcher odd-even sort of u64[8] ascending (19 comparators)
#define SORT8U(d)                                          \
  CEU(d, 0, 1) CEU(d, 2, 3) CEU(d, 4, 5) CEU(d, 6, 7)      \
  CEU(d, 0, 2) CEU(d, 1, 3) CEU(d, 4, 6) CEU(d, 5, 7)      \
  CEU(d, 1, 2) CEU(d, 5, 6)                                \
  CEU(d, 0, 4) CEU(d, 1, 5) CEU(d, 2, 6) CEU(d, 3, 7)      \
  CEU(d, 2, 4) CEU(d, 3, 5)                                \
  CEU(d, 1, 2) CEU(d, 3, 4) CEU(d, 5, 6)

// bitonic-8 sorter (input must be bitonic) -- u64, 12 comparators
#define BSORT8U(d)                                         \
  CEU(d, 0, 4) CEU(d, 1, 5) CEU(d, 2, 6) CEU(d, 3, 7)      \
  CEU(d, 0, 2) CEU(d, 1, 3) CEU(d, 4, 6) CEU(d, 5, 7)      \
  CEU(d, 0, 1) CEU(d, 2, 3) CEU(d, 4, 5) CEU(d, 6, 7)

// bitonic sort of L[16] (input bitonic) ascending: 32 comparators -- float
#define BITONIC16(L)                                                      \
  CE(L, 0, 8) CE(L, 1, 9) CE(L, 2, 10) CE(L, 3, 11) CE(L, 4, 12)          \
  CE(L, 5, 13) CE(L, 6, 14) CE(L, 7, 15)                                  \
  CE(L, 0, 4) CE(L, 1, 5) CE(L, 2, 6) CE(L, 3, 7) CE(L, 8, 12)            \
  CE(L, 9, 13) CE(L, 10, 14) CE(L, 11, 15)                                \
  CE(L, 0, 2) CE(L, 1, 3) CE(L, 4, 6) CE(L, 5, 7) CE(L, 8, 10)            \
  CE(L, 9, 11) CE(L, 12, 14) CE(L, 13, 15)                                \
  CE(L, 0, 1) CE(L, 2, 3) CE(L, 4, 5) CE(L, 6, 7) CE(L, 8, 9)             \
  CE(L, 10, 11) CE(L, 12, 13) CE(L, 14, 15)

// FMA packed-pair distance: 8 points -> 4 f2 of d^2 approx. 6 pk-ops/pair
// (3 sub, 1 mul, 2 fma -> v_pk_fma_f32). Used ONLY for candidate filtering
// with an inflated threshold; exact ordering uses d2rn in phase 3.
__device__ __forceinline__ void dist8f(const float* px, const float* py,
                                       const float* pz, int base, float qx,
                                       float qy, float qz, f2 dd[4]) {
  const f4 X0 = *(const f4*)&px[base];
  const f4 X1 = *(const f4*)&px[base + 4];
  const f4 Y0 = *(const f4*)&py[base];
  const f4 Y1 = *(const f4*)&py[base + 4];
  const f4 Z0 = *(const f4*)&pz[base];
  const f4 Z1 = *(const f4*)&pz[base + 4];
  const f2 qvx = {qx, qx}, qvy = {qy, qy}, qvz = {qz, qz};
  {
    const f2 dx = qvx - X0.xy, dy = qvy - Y0.xy, dz = qvz - Z0.xy;
    dd[0] = __builtin_elementwise_fma(
        dz, dz, __builtin_elementwise_fma(dy, dy, dx * dx));
  }
  {
    const f2 dx = qvx - X0.zw, dy = qvy - Y0.zw, dz = qvz - Z0.zw;
    dd[1] = __builtin_elementwise_fma(
        dz, dz, __builtin_elementwise_fma(dy, dy, dx * dx));
  }
  {
    const f2 dx = qvx - X1.xy, dy = qvy - Y1.xy, dz = qvz - Z1.xy;
    dd[2] = __builtin_elementwise_fma(
        dz, dz, __builtin_elementwise_fma(dy, dy, dx * dx));
  }
  {
    const f2 dx = qvx - X1.zw, dy = qvy - Y1.zw, dz = qvz - Z1.zw;
    dd[3] = __builtin_elementwise_fma(
        dz, dz, __builtin_elementwise_fma(dy, dy, dx * dx));
  }
}

__device__ __forceinline__ float min8p(const f2 dd[4]) {
  return fminf(fminf(fminf(dd[0].x, dd[0].y), fminf(dd[1].x, dd[1].y)),
               fminf(fminf(dd[2].x, dd[2].y), fminf(dd[3].x, dd[3].y)));
}

// ---------------------------------------------------------------------------
// Fused kernel (r14 structure); delta: FMA distances in pass 1/2 with
// threshold inflated by (1+4e-6). Phase 3 unchanged (exact d2rn).
// ---------------------------------------------------------------------------
__global__ __launch_bounds__(256, 4) void fused_kernel(
    const float* __restrict__ features, const float* __restrict__ W1,
    const float* __restrict__ b1, float* __restrict__ out_feats,
    float* __restrict__ out_x, const float* __restrict__ xyz,
    const float* __restrict__ xyz_fp, float* __restrict__ out_knn) {
  __shared__ __align__(16) unsigned char smem[SMEM_BYTES];

  const int b = blockIdx.y;
  const int t = threadIdx.x;

  if (blockIdx.x >= KB) {
    // ================= feats + linear path (verbatim r7) =================
    float(*tile)[68] = reinterpret_cast<float(*)[68]>(smem);  // 17408 B

    const int n0 = (blockIdx.x - KB) * 64;
    const int lane = t & 63;
    const int grp = t >> 6;

    for (int c = grp; c < NC; c += 4)
      tile[c][lane] = features[((size_t)(b * NC + c) * NN) + n0 + lane];

    float4 wreg[16];
    {
      const float4* Wr = (const float4*)(W1 + lane * NC);
#pragma unroll
      for (int k = 0; k < 16; k++) wreg[k] = Wr[k];
    }
    __syncthreads();

    for (int j = grp; j < 64; j += 4)
      out_feats[((size_t)(b * NN + n0 + j) * NC) + lane] = tile[lane][j];

    const int d = lane;
    float acc[16];
    const float bd = b1[d];
#pragma unroll
    for (int jj = 0; jj < 16; jj++) acc[jj] = bd;

    const float4* tv = (const float4*)&tile[0][0];
#pragma unroll
    for (int k = 0; k < 16; k++) {
#pragma unroll
      for (int cc = 0; cc < 4; cc++) {
        const int c = k * 4 + cc;
        const float w = (cc == 0)   ? wreg[k].x
                        : (cc == 1) ? wreg[k].y
                        : (cc == 2) ? wreg[k].z
                                    : wreg[k].w;
#pragma unroll
        for (int q = 0; q < 4; q++) {
          const float4 v = tv[c * 17 + grp * 4 + q];
          acc[q * 4 + 0] = fmaf(v.x, w, acc[q * 4 + 0]);
          acc[q * 4 + 1] = fmaf(v.y, w, acc[q * 4 + 1]);
          acc[q * 4 + 2] = fmaf(v.z, w, acc[q * 4 + 2]);
          acc[q * 4 + 3] = fmaf(v.w, w, acc[q * 4 + 3]);
        }
      }
    }
#pragma unroll
    for (int jj = 0; jj < 16; jj++) {
      const int j = grp * 16 + jj;
      out_x[((size_t)(b * NN + n0 + j) * ND) + d] = acc[jj];
    }
    return;
  }

  // ======================= kNN path =======================
  float* px = reinterpret_cast<float*>(smem);
  float* py = px + PARTS * CHUNK;
  float* pz = py + PARTS * CHUNK;
  unsigned short* cand =
      reinterpret_cast<unsigned short*>(smem + 3 * PARTS * CHUNK * 4);
  int* ccnt =
      reinterpret_cast<int*>(smem + 3 * PARTS * CHUNK * 4 + QPB * CSTR * 2);

  const int ql = t >> 3;   // query-local 0..31 (lanes ql*8..ql*8+7: one wave)
  const int part = t & 7;  // 0..7

  if (t < QPB) ccnt[t] = 0;

  // stage points SoA into swizzled slots
  const float* P = xyz + (size_t)b * NN * 3;
  for (int i = t; i < NN; i += 256) {
    const int slot = slotOf(i);
    px[slot] = P[3 * i + 0];
    py[slot] = P[3 * i + 1];
    pz[slot] = P[3 * i + 2];
  }
  __syncthreads();  // the ONLY block barrier: staging + ccnt init visibility

  const int q = blockIdx.x * QPB + ql;
  const float* Q = xyz_fp + ((size_t)b * NM + q) * 3;
  const float qx = Q[0], qy = Q[1], qz = Q[2];

  const int pbase = part * CHUNK;

  // ---- pass 1: group mins (FMA metric) ----
  float gmin[NG];
#pragma unroll
  for (int g = 0; g < NG; g++) {
    float gm = 3.0e38f;
#pragma unroll
    for (int bb = 0; bb < 4; bb++) {
      const int B = g * 4 + bb;
      const int BS = B ^ (B >> 2);
      f2 dd[4];
      dist8f(px, py, pz, pbase + BS * 8, qx, qy, qz, dd);
      gm = fminf(gm, min8p(dd));
    }
    gmin[g] = gm;
  }

  // ---- T = 16th-smallest of the query's 64 group-mins (FMA metric) ----
  float s[16];
  {
    float g8[NG];
#pragma unroll
    for (int g = 0; g < NG; g++) g8[g] = gmin[g];
    SORT8(g8)
#pragma unroll
    for (int j = 0; j < 8; j++) s[j] = g8[j];
#pragma unroll
    for (int j = 8; j < 16; j++) s[j] = 3.0e38f;
  }
#pragma unroll
  for (int mask = 1; mask <= 4; mask <<= 1) {
    float B[16];
#pragma unroll
    for (int j = 0; j < 16; j++) B[j] = __shfl_xor(s[j], mask, 64);
    float L[16];
#pragma unroll
    for (int j = 0; j < 16; j++) L[j] = fminf(s[j], B[15 - j]);
    BITONIC16(L)
#pragma unroll
    for (int j = 0; j < 16; j++) s[j] = L[j];
  }
  // inflate: absorbs FMA-vs-exact rounding skew (proof: any exact-top-16
  // point has dFMA <= T*(1+3*4ulp) << T*(1+4e-6)). Superset preserved.
  const float T = s[15] * (1.0f + 4e-6f);

  // ---- per-lane 8-bit pass mask ----
  unsigned m8 = 0;
#pragma unroll
  for (int g = 0; g < NG; g++) m8 |= (gmin[g] <= T) ? (1u << g) : 0u;

  // ---- butterfly-OR across the query's 8 lanes -> 64-bit group mask ----
  unsigned lo = (part < 4) ? (m8 << (8 * part)) : 0u;
  unsigned hi = (part >= 4) ? (m8 << (8 * (part - 4))) : 0u;
#pragma unroll
  for (int mk = 1; mk <= 4; mk <<= 1) {
    lo |= __shfl_xor(lo, mk, 64);
    hi |= __shfl_xor(hi, mk, 64);
  }
  const unsigned long long vm = ((unsigned long long)hi << 32) | lo;

  // ---- round-robin: k-th set bit -> lane (k & 7) ----
  unsigned long long mym = 0ull;
  {
    unsigned long long m = vm;
    int cnt = 0;
    while (m) {
      const unsigned long long lb = m & (0ull - m);
      if ((cnt & 7) == part) mym |= lb;
      m ^= lb;
      cnt++;
    }
  }

  // ---- pass 2: scan assigned groups; batched slot reservation.
  //      All writes/atomics hit only this query's row -> intra-wave. ----
  while (mym) {
    const int gid = __ffsll(mym) - 1;
    mym &= mym - 1;
    const int cb = (gid >> 3) * CHUNK;
    const int goff = gid & 7;
    const int ib = (gid >> 3) * PPT + goff * 32;
#pragma unroll
    for (int bb = 0; bb < 4; bb++) {
      const int B = goff * 4 + bb;
      const int BS = B ^ (B >> 2);
      f2 dd[4];
      dist8f(px, py, pz, cb + BS * 8, qx, qy, qz, dd);
      if (min8p(dd) <= T) {
        unsigned am = 0;
#pragma unroll
        for (int k = 0; k < 4; k++) {
          am |= (dd[k].x <= T) ? (1u << (2 * k)) : 0u;
          am |= (dd[k].y <= T) ? (1u << (2 * k + 1)) : 0u;
        }
        int pos = atomicAdd(&ccnt[ql], __popc(am));
        while (am) {
          const int k = __ffs(am) - 1;
          am &= am - 1;
          if (pos < CAP)
            cand[ql * CSTR + pos] = (unsigned short)(ib + bb * 8 + k);
          pos++;
        }
      }
    }
  }
  // NO barrier: phase 3 reads only this wave's writes (in-order per wave)

  // ---- phase 3: exact top-16 (d2rn keys), 8-lane parallel ----
  {
    const int cnt = ccnt[ql];
    if (cnt <= CAP) {
      unsigned long long kb8[8];
      // gather this lane's strided candidates: part, part+8, ...
#pragma unroll
      for (int i = 0; i < 8; i++) {
        const int c = part + 8 * i;
        unsigned long long kk = ~0ULL;
        if (c < cnt) {
          const int idx = cand[ql * CSTR + c];
          const int slot = slotOf(idx);
          const float d2 = d2rn(qx, qy, qz, px[slot], py[slot], pz[slot]);
          kk = ((unsigned long long)__float_as_uint(d2) << 32) | (unsigned)idx;
        }
        kb8[i] = kk;
      }
      SORT8U(kb8)

      // round 1 (XOR 1): pair merge -> sorted-16 per lane pair
      {
        unsigned long long bb[8];
#pragma unroll
        for (int j = 0; j < 8; j++) bb[j] = __shfl_xor(kb8[7 - j], 1, 64);
        if (part & 1) {
#pragma unroll
          for (int j = 0; j < 8; j++)
            kb8[j] = (kb8[j] < bb[j]) ? bb[j] : kb8[j];
        } else {
#pragma unroll
          for (int j = 0; j < 8; j++)
            kb8[j] = (kb8[j] < bb[j]) ? kb8[j] : bb[j];
        }
        BSORT8U(kb8)
      }

      // rounds 2,3 (XOR 3 then XOR 5): merge sorted-16s, keep top-16
#pragma unroll
      for (int r = 0; r < 2; r++) {
        const int xm = r ? 5 : 3;
        unsigned long long bb[8];
#pragma unroll
        for (int j = 0; j < 8; j++) bb[j] = __shfl_xor(kb8[7 - j], xm, 64);
#pragma unroll
        for (int j = 0; j < 8; j++)
          kb8[j] = (kb8[j] < bb[j]) ? kb8[j] : bb[j];
#pragma unroll
        for (int j = 0; j < 8; j++) bb[j] = __shfl_xor(kb8[j], 1, 64);
        if (part & 1) {
#pragma unroll
          for (int j = 0; j < 8; j++)
            kb8[j] = (kb8[j] < bb[j]) ? bb[j] : kb8[j];
        } else {
#pragma unroll
          for (int j = 0; j < 8; j++)
            kb8[j] = (kb8[j] < bb[j]) ? kb8[j] : bb[j];
        }
        BSORT8U(kb8)
      }

      // final sorted-16: even lane holds ranks 0-7, odd lane ranks 8-15
      if (part < 2) {
#pragma unroll
        for (int j = 0; j < 8; j++)
          cand[ql * CSTR + part * 8 + j] = (unsigned short)(unsigned)kb8[j];
      }
    } else if (part == 0) {
      // overflow fallback (astronomically rare): serial exact scan
      unsigned long long kb[NK];
#pragma unroll
      for (int j = 0; j < NK; j++) kb[j] = ~0ULL;
      for (int i = 0; i < NN; i++) {
        const int slot = slotOf(i);
        const float d2 = d2rn(qx, qy, qz, px[slot], py[slot], pz[slot]);
        unsigned long long kk =
            ((unsigned long long)__float_as_uint(d2) << 32) | (unsigned)i;
        if (kk < kb[NK - 1]) {
#pragma unroll
          for (int j = 0; j < NK; j++) {
            const bool c2 = kk < kb[j];
            const unsigned long long lo2 = c2 ? kk : kb[j];
            const unsigned long long hi2 = c2 ? kb[j] : kk;
            kb[j] = lo2;
            kk = hi2;
          }
        }
      }
#pragma unroll
      for (int j = 0; j < NK; j++)
        cand[ql * CSTR + j] = (unsigned short)(unsigned)kb[j];
    }
  }
  // NO barrier: output reads only this wave's phase-3 writes

  // ---- output: each part lane writes 2 neighbors (6 floats) ----
  float* o = out_knn + ((size_t)(b * NM + q)) * (NK * 3);
#pragma unroll
  for (int jj = 0; jj < 2; jj++) {
    const int j = part * 2 + jj;
    const int i = cand[ql * CSTR + j];
    const int slot = slotOf(i);
    o[3 * j + 0] = px[slot];
    o[3 * j + 1] = py[slot];
    o[3 * j + 2] = pz[slot];
  }
}

// ---------------------------------------------------------------------------
extern "C" void kernel_launch(void* const* d_in, const int* in_sizes, int n_in,
                              void* d_out, int out_size, void* d_ws,
                              size_t ws_size, hipStream_t stream) {
  const float* xyz      = (const float*)d_in[0];  // [8,2048,3]
  const float* xyz_fp   = (const float*)d_in[1];  // [8,8192,3]
  const float* features = (const float*)d_in[2];  // [8,64,2048]
  const float* W1 = (const float*)d_in[4];        // [64,64]
  const float* b1 = (const float*)d_in[5];        // [64]

  float* out_feats = (float*)d_out;                       // 8*2048*64
  float* out_knn   = out_feats + (size_t)NB * NN * NC;    // 8*8192*16*3
  float* out_x     = out_knn + (size_t)NB * NM * NK * 3;  // 8*2048*64

  fused_kernel<<<dim3(KB + FB, NB), 256, 0, stream>>>(
      features, W1, b1, out_feats, out_x, xyz, xyz_fp, out_knn);
}